// Round 1
// baseline (39194.794 us; speedup 1.0000x reference)
//
#include <hip/hip_runtime.h>
#include <math.h>

#define Bn 4
#define Sn 1024
#define Dn 512
#define NHn 8
#define HDn 64
#define KNn 16384
#define KLn 8
#define NCn 4
#define Mn (Bn*Sn)   // 4096 rows

// ---------------- helpers ----------------

__device__ __forceinline__ float wred_sum(float v){
  #pragma unroll
  for (int m=1;m<64;m<<=1) v += __shfl_xor(v, m, 64);
  return v;
}

__device__ __forceinline__ bool better(float v, int i, float v2, int i2){
  return (v>v2) || (v==v2 && i<i2);
}

__device__ __forceinline__ void top4_insert(float v, int gi, float tv[4], int ti[4]){
  if (better(v, gi, tv[3], ti[3])){
    tv[3]=v; ti[3]=gi;
    #pragma unroll
    for (int s=3;s>0;s--){
      if (better(tv[s],ti[s],tv[s-1],ti[s-1])){
        float fv=tv[s]; tv[s]=tv[s-1]; tv[s-1]=fv;
        int ii=ti[s]; ti[s]=ti[s-1]; ti[s-1]=ii;
      }
    }
  }
}

// ---------------- 1. RMSNorm(x) -> hn ----------------

__global__ __launch_bounds__(256) void rmsnorm_kernel(const float* __restrict__ x,
                                                      const float* __restrict__ w,
                                                      float* __restrict__ y){
  int row = blockIdx.x, tid = threadIdx.x;
  const float2* xr = (const float2*)(x + (size_t)row*Dn);
  float2 v = xr[tid];
  float ss = v.x*v.x + v.y*v.y;
  ss = wred_sum(ss);
  __shared__ float red[4];
  int wid = tid>>6, lane = tid&63;
  if (lane==0) red[wid]=ss;
  __syncthreads();
  float tot = red[0]+red[1]+red[2]+red[3];
  float sc = rsqrtf(tot*(1.0f/Dn) + 1e-5f);
  float2 wv = ((const float2*)w)[tid];
  ((float2*)(y + (size_t)row*Dn))[tid] = make_float2(v.x*sc*wv.x, v.y*sc*wv.y);
}

// ------------- 2. QKV GEMM (+RoPE) with relayout to (B,NH,S,HD) -------------
// A: (4096,512) row-major, Bw: (512,512) row-major. 64x64 tile, 4x4/thread.

__global__ __launch_bounds__(256) void gemm_qkv_kernel(const float* __restrict__ A,
                                                       const float* __restrict__ Bw,
                                                       const float* __restrict__ pc,
                                                       const float* __restrict__ ps,
                                                       float* __restrict__ out, int rope){
  __shared__ float As[16][68];
  __shared__ float Bs[16][68];
  int tid=threadIdx.x, tx=tid&15, ty=tid>>4;
  int n0 = blockIdx.x*64, m0 = blockIdx.y*64;
  float acc[4][4] = {};
  for (int kt=0; kt<Dn; kt+=16){
    #pragma unroll
    for (int t=0;t<4;t++){ int i=tid+t*256; int r=i>>4, c=i&15; As[c][r]=A[(size_t)(m0+r)*Dn + kt+c]; }
    #pragma unroll
    for (int t=0;t<4;t++){ int i=tid+t*256; int r=i>>6, c=i&63; Bs[r][c]=Bw[(size_t)(kt+r)*Dn + n0+c]; }
    __syncthreads();
    #pragma unroll
    for (int kk=0;kk<16;kk++){
      float a[4], b[4];
      #pragma unroll
      for (int i=0;i<4;i++) a[i]=As[kk][ty*4+i];
      #pragma unroll
      for (int j=0;j<4;j++) b[j]=Bs[kk][tx*4+j];
      #pragma unroll
      for (int i=0;i<4;i++)
        #pragma unroll
        for (int j=0;j<4;j++) acc[i][j] += a[i]*b[j];
    }
    __syncthreads();
  }
  #pragma unroll
  for (int i=0;i<4;i++){
    int mm = m0+ty*4+i; int b = mm>>10; int s = mm&1023;
    #pragma unroll
    for (int j=0;j<4;j+=2){
      int n = n0+tx*4+j; int h = n>>6; int d = n&63;
      size_t o = ((size_t)(b*NHn+h)*Sn + s)*HDn + d;
      float a0=acc[i][j], a1=acc[i][j+1];
      if (rope){
        float c = pc[s*32 + (d>>1)], sn = ps[s*32 + (d>>1)];
        out[o]   = a0*c - a1*sn;
        out[o+1] = a0*sn + a1*c;
      } else { out[o]=a0; out[o+1]=a1; }
    }
  }
}

// ---------------- generic f32 GEMM: C = A(MxK) @ B(KxN), row-major ----------------

__global__ __launch_bounds__(256) void gemm_f32_kernel(const float* __restrict__ A,
                                                       const float* __restrict__ Bw,
                                                       float* __restrict__ C, int K, int N){
  __shared__ float As[16][68];
  __shared__ float Bs[16][68];
  int tid=threadIdx.x, tx=tid&15, ty=tid>>4;
  int n0 = blockIdx.x*64, m0 = blockIdx.y*64;
  float acc[4][4] = {};
  for (int kt=0; kt<K; kt+=16){
    #pragma unroll
    for (int t=0;t<4;t++){ int i=tid+t*256; int r=i>>4, c=i&15; As[c][r]=A[(size_t)(m0+r)*K + kt+c]; }
    #pragma unroll
    for (int t=0;t<4;t++){ int i=tid+t*256; int r=i>>6, c=i&63; Bs[r][c]=Bw[(size_t)(kt+r)*N + n0+c]; }
    __syncthreads();
    #pragma unroll
    for (int kk=0;kk<16;kk++){
      float a[4], b[4];
      #pragma unroll
      for (int i=0;i<4;i++) a[i]=As[kk][ty*4+i];
      #pragma unroll
      for (int j=0;j<4;j++) b[j]=Bs[kk][tx*4+j];
      #pragma unroll
      for (int i=0;i<4;i++)
        #pragma unroll
        for (int j=0;j<4;j++) acc[i][j] += a[i]*b[j];
    }
    __syncthreads();
  }
  #pragma unroll
  for (int i=0;i<4;i++)
    #pragma unroll
    for (int j=0;j<4;j++)
      C[(size_t)(m0+ty*4+i)*N + n0+tx*4+j] = acc[i][j];
}

// ---------------- 3. causal flash attention, f32, 64x64 tiles ----------------
// q,k,v layout (B*NH, S, HD); out layout (B, S, NH, HD) == (B,S,D)

__global__ __launch_bounds__(256) void attn_kernel(const float* __restrict__ q,
                                                   const float* __restrict__ k,
                                                   const float* __restrict__ v,
                                                   float* __restrict__ o){
  __shared__ float Qs[64][65];
  __shared__ float KPs[64][65];   // K tile, then reused for P (scores)
  __shared__ float Vs[64][65];
  __shared__ float mArr[64], lArr[64], aArr[64];
  int tid=threadIdx.x, tx=tid&15, ty=tid>>4;
  int qt=blockIdx.x, bh=blockIdx.y;
  const float* Qp = q + (size_t)bh*Sn*HDn + (size_t)qt*64*HDn;
  const float* Kp = k + (size_t)bh*Sn*HDn;
  const float* Vp = v + (size_t)bh*Sn*HDn;
  #pragma unroll
  for (int t=0;t<16;t++){ int i=tid+t*256; int r=i>>6, c=i&63; Qs[r][c]=Qp[(size_t)r*64+c]; }
  if (tid<64){ mArr[tid]=-1e30f; lArr[tid]=0.f; }
  float O[4][4] = {};
  __syncthreads();
  for (int kt=0; kt<=qt; kt++){
    #pragma unroll
    for (int t=0;t<16;t++){
      int i=tid+t*256; int r=i>>6, c=i&63;
      KPs[r][c]=Kp[(size_t)(kt*64+r)*64+c];
      Vs[r][c] =Vp[(size_t)(kt*64+r)*64+c];
    }
    __syncthreads();
    float sc[4][4] = {};
    #pragma unroll 8
    for (int d=0; d<64; d++){
      float a[4], b[4];
      #pragma unroll
      for (int i=0;i<4;i++) a[i]=Qs[ty*4+i][d];
      #pragma unroll
      for (int j=0;j<4;j++) b[j]=KPs[tx*4+j][d];
      #pragma unroll
      for (int i=0;i<4;i++)
        #pragma unroll
        for (int j=0;j<4;j++) sc[i][j] += a[i]*b[j];
    }
    __syncthreads();   // all K reads done; safe to overwrite with P
    #pragma unroll
    for (int i=0;i<4;i++){
      int qg = qt*64+ty*4+i;
      #pragma unroll
      for (int j=0;j<4;j++){
        int kg = kt*64+tx*4+j;
        KPs[ty*4+i][tx*4+j] = (kg<=qg) ? sc[i][j]*0.125f : -1e9f;
      }
    }
    __syncthreads();
    if (tid<64){
      int r=tid;
      float mt=-1e30f;
      for (int c=0;c<64;c++) mt=fmaxf(mt, KPs[r][c]);
      float mn = fmaxf(mArr[r], mt);
      float al = __expf(mArr[r]-mn);
      float sum=0.f;
      for (int c=0;c<64;c++){ float p=__expf(KPs[r][c]-mn); KPs[r][c]=p; sum+=p; }
      lArr[r]=lArr[r]*al+sum; mArr[r]=mn; aArr[r]=al;
    }
    __syncthreads();
    #pragma unroll
    for (int i=0;i<4;i++){ float al=aArr[ty*4+i];
      #pragma unroll
      for (int j=0;j<4;j++) O[i][j]*=al; }
    #pragma unroll 8
    for (int kk=0; kk<64; kk++){
      float p[4], vv[4];
      #pragma unroll
      for (int i=0;i<4;i++) p[i]=KPs[ty*4+i][kk];
      #pragma unroll
      for (int j=0;j<4;j++) vv[j]=Vs[kk][tx*4+j];
      #pragma unroll
      for (int i=0;i<4;i++)
        #pragma unroll
        for (int j=0;j<4;j++) O[i][j] += p[i]*vv[j];
    }
    __syncthreads();
  }
  int b=bh>>3, h=bh&7;
  #pragma unroll
  for (int i=0;i<4;i++){
    int qg = qt*64+ty*4+i;
    float inv = 1.f/lArr[ty*4+i];
    #pragma unroll
    for (int j=0;j<4;j++)
      o[((size_t)(b*Sn+qg))*Dn + h*HDn + tx*4+j] = O[i][j]*inv;
  }
}

// ---------------- 5. h = x + h_attn ; hm = rms(h_attn)*w -> cat[:, :512] ----------------

__global__ __launch_bounds__(256) void h_hm_kernel(const float* __restrict__ x,
                                                   const float* __restrict__ ha,
                                                   const float* __restrict__ w,
                                                   float* __restrict__ h,
                                                   float* __restrict__ cat){
  int row=blockIdx.x, tid=threadIdx.x;
  float2 a = ((const float2*)(ha + (size_t)row*Dn))[tid];
  float2 xv = ((const float2*)(x + (size_t)row*Dn))[tid];
  float ss = a.x*a.x + a.y*a.y;
  ss = wred_sum(ss);
  __shared__ float red[4];
  int wid=tid>>6, lane=tid&63;
  if (lane==0) red[wid]=ss;
  __syncthreads();
  float tot = red[0]+red[1]+red[2]+red[3];
  float sc = rsqrtf(tot*(1.0f/Dn) + 1e-5f);
  float2 wv = ((const float2*)w)[tid];
  ((float2*)(h + (size_t)row*Dn))[tid] = make_float2(xv.x+a.x, xv.y+a.y);
  ((float2*)(cat + (size_t)row*1024))[tid] = make_float2(a.x*sc*wv.x, a.y*sc*wv.y);
}

// ---------------- 6. logits GEMM (128x128 tile, 8x8/thread) + fused per-tile top4 ----------------
// A = cat (lda=1024, first 512 cols are hm), B = w_gate (512 x 16384)

__global__ __launch_bounds__(256) void logits_topk_kernel(const float* __restrict__ A,
                                                          const float* __restrict__ Bg,
                                                          float* __restrict__ topv,
                                                          int* __restrict__ topi){
  __shared__ float As[16][136];
  __shared__ float Bs[16][136];
  int tid=threadIdx.x, tx=tid&15, ty=tid>>4;
  int n0 = blockIdx.x*128, m0 = blockIdx.y*128;
  float acc[8][8] = {};
  for (int kt=0; kt<Dn; kt+=16){
    #pragma unroll
    for (int t=0;t<8;t++){ int i=tid+t*256; int r=i>>4, c=i&15; As[c][r]=A[(size_t)(m0+r)*1024 + kt+c]; }
    #pragma unroll
    for (int t=0;t<8;t++){ int i=tid+t*256; int r=i>>7, c=i&127; Bs[r][c]=Bg[(size_t)(kt+r)*KNn + n0+c]; }
    __syncthreads();
    #pragma unroll
    for (int kk=0;kk<16;kk++){
      float4 a0 = *(const float4*)&As[kk][ty*8];
      float4 a1 = *(const float4*)&As[kk][ty*8+4];
      float4 b0 = *(const float4*)&Bs[kk][tx*8];
      float4 b1 = *(const float4*)&Bs[kk][tx*8+4];
      float a[8]={a0.x,a0.y,a0.z,a0.w,a1.x,a1.y,a1.z,a1.w};
      float b[8]={b0.x,b0.y,b0.z,b0.w,b1.x,b1.y,b1.z,b1.w};
      #pragma unroll
      for (int i=0;i<8;i++)
        #pragma unroll
        for (int j=0;j<8;j++) acc[i][j] += a[i]*b[j];
    }
    __syncthreads();
  }
  // per-row top-4 within this 128-col tile (across the 16 tx lanes of each ty group)
  #pragma unroll 1
  for (int i=0;i<8;i++){
    int row = m0 + ty*8 + i;
    float tv[4] = {-INFINITY,-INFINITY,-INFINITY,-INFINITY};
    int   ti4[4] = {0x7fffffff,0x7fffffff,0x7fffffff,0x7fffffff};
    #pragma unroll
    for (int j=0;j<8;j++) top4_insert(acc[i][j], n0+tx*8+j, tv, ti4);
    int ptr=0;
    #pragma unroll 1
    for (int r=0;r<4;r++){
      float cv = (ptr<4)? tv[ptr] : -INFINITY;
      int   ci = (ptr<4)? ti4[ptr] : 0x7fffffff;
      #pragma unroll
      for (int mask=1; mask<16; mask<<=1){
        float ov = __shfl_xor(cv, mask, 16);
        int   oi = __shfl_xor(ci, mask, 16);
        if (ov>cv || (ov==cv && oi<ci)) { cv=ov; ci=oi; }
      }
      if (ptr<4 && ti4[ptr]==ci) ptr++;
      if (tx==0){
        topv[((size_t)row*128 + blockIdx.x)*4 + r] = cv;
        topi[((size_t)row*128 + blockIdx.x)*4 + r] = ci;
      }
    }
  }
}

// ---------------- 7. merge 128 tile-partials -> global top4 (sorted desc) ----------------

__global__ __launch_bounds__(256) void merge_topk_kernel(const float* __restrict__ topv,
                                                         const int* __restrict__ topi,
                                                         int* __restrict__ cand){
  int tid=threadIdx.x, wid=tid>>6, lane=tid&63;
  int row = blockIdx.x*4 + wid;
  float tv[4] = {-INFINITY,-INFINITY,-INFINITY,-INFINITY};
  int   ti4[4] = {0x7fffffff,0x7fffffff,0x7fffffff,0x7fffffff};
  #pragma unroll
  for (int e=0;e<8;e++){
    int idx = e*64 + lane;
    top4_insert(topv[(size_t)row*512 + idx], topi[(size_t)row*512 + idx], tv, ti4);
  }
  int ptr=0;
  #pragma unroll 1
  for (int r=0;r<4;r++){
    float cv = (ptr<4)? tv[ptr] : -INFINITY;
    int   ci = (ptr<4)? ti4[ptr] : 0x7fffffff;
    #pragma unroll
    for (int mask=1; mask<64; mask<<=1){
      float ov = __shfl_xor(cv, mask, 64);
      int   oi = __shfl_xor(ci, mask, 64);
      if (ov>cv || (ov==cv && oi<ci)) { cv=ov; ci=oi; }
    }
    if (ptr<4 && ti4[ptr]==ci) ptr++;
    if (lane==0) cand[(size_t)row*4 + r] = ci;
  }
}

// ------- 8. gather cand_mem, sim, gumbel select, losses, write sel_mem -> cat[:,512:] -------

__global__ __launch_bounds__(256) void select_kernel(const float* __restrict__ cat,
                                                     const int* __restrict__ cand,
                                                     const int* __restrict__ mem_bank,
                                                     const float* __restrict__ tok_emb,
                                                     const float* __restrict__ gu,
                                                     float* __restrict__ cat_out,
                                                     float* __restrict__ losses){
  __shared__ float cm[4][512];
  __shared__ int ids[32];
  __shared__ float wred[15][4];
  __shared__ int sel_s;
  int row=blockIdx.x, tid=threadIdx.x;
  if (tid<32) ids[tid] = mem_bank[(size_t)cand[(size_t)row*4 + (tid>>3)]*KLn + (tid&7)];
  __syncthreads();
  #pragma unroll
  for (int n=0;n<4;n++){
    float s0=0.f, s1=0.f;
    #pragma unroll
    for (int l=0;l<8;l++){
      const float* e = tok_emb + (size_t)ids[n*8+l]*Dn;
      s0 += e[tid]; s1 += e[tid+256];
    }
    cm[n][tid]=s0*0.125f; cm[n][tid+256]=s1*0.125f;
  }
  __syncthreads();
  float hm0 = cat[(size_t)row*1024 + tid], hm1 = cat[(size_t)row*1024 + 256 + tid];
  float c0[4], c1[4];
  #pragma unroll
  for (int n=0;n<4;n++){ c0[n]=cm[n][tid]; c1[n]=cm[n][tid+256]; }
  float p[15];
  p[0]=hm0*hm0+hm1*hm1;
  #pragma unroll
  for (int n=0;n<4;n++) p[1+n]=hm0*c0[n]+hm1*c1[n];
  int qi=5;
  #pragma unroll
  for (int n=0;n<4;n++)
    #pragma unroll
    for (int m=n;m<4;m++) p[qi++]=c0[n]*c0[m]+c1[n]*c1[m];
  int wid=tid>>6, lane=tid&63;
  #pragma unroll
  for (int i=0;i<15;i++) p[i]=wred_sum(p[i]);
  if (lane==0){
    #pragma unroll
    for (int i=0;i<15;i++) wred[i][wid]=p[i];
  }
  __syncthreads();
  if (tid==0){
    float tot[15];
    #pragma unroll
    for (int i=0;i<15;i++) tot[i]=wred[i][0]+wred[i][1]+wred[i][2]+wred[i][3];
    float hn2 = fmaxf(sqrtf(tot[0]), 1e-8f);
    const int diag[4]={5,9,12,14};
    float sim[4], dn[4];
    #pragma unroll
    for (int n=0;n<4;n++){
      float cn = sqrtf(tot[diag[n]]);
      sim[n] = tot[1+n]/(hn2*fmaxf(cn,1e-8f));
      dn[n]  = fmaxf(cn,1e-12f);
    }
    float best=-1e30f; int sel=0;
    #pragma unroll
    for (int n=0;n<4;n++){
      float u = gu[(size_t)row*4+n];
      float g = -logf(-logf(u + 1e-20f) + 1e-20f);
      float a = sim[n]+g;
      if (a>best){ best=a; sel=n; }
    }
    atomicAdd(&losses[0], sim[sel]);
    const int cross[6]={6,7,8,10,11,13};
    const int cn_[6]={0,0,0,1,1,2}, cm_[6]={1,2,3,2,3,3};
    float dv=0.f;
    #pragma unroll
    for (int t=0;t<6;t++) dv += 2.f*tot[cross[t]]/(dn[cn_[t]]*dn[cm_[t]]);
    atomicAdd(&losses[1], dv);
    sel_s=sel;
  }
  __syncthreads();
  int sel=sel_s;
  cat_out[(size_t)row*1024 + 512 + tid]       = cm[sel][tid];
  cat_out[(size_t)row*1024 + 512 + 256 + tid] = cm[sel][tid+256];
}

// ---------------- 12. out = h + sigmoid(g+bg)*(m+bm); losses tail ----------------

__global__ __launch_bounds__(256) void final_kernel(const float* __restrict__ h,
                                                    const float* __restrict__ g,
                                                    const float* __restrict__ m,
                                                    const float* __restrict__ bg,
                                                    const float* __restrict__ bm,
                                                    const float* __restrict__ losses,
                                                    float* __restrict__ out){
  int idx = blockIdx.x*256 + threadIdx.x;
  int n = idx & (Dn-1);
  float gl = g[idx] + bg[n];
  float ml = m[idx] + bm[n];
  float gate = 1.f/(1.f+__expf(-gl));
  out[idx] = h[idx] + gate*ml;
  if (idx==0){
    out[(size_t)Mn*Dn]     = -losses[0]*(1.f/(float)Mn);
    out[(size_t)Mn*Dn + 1] =  losses[1]*(1.f/(float)(Mn*NCn*(NCn-1)));
  }
}

// ---------------- launch ----------------

extern "C" void kernel_launch(void* const* d_in, const int* in_sizes, int n_in,
                              void* d_out, int out_size, void* d_ws, size_t ws_size,
                              hipStream_t stream){
  const float* x           = (const float*)d_in[0];
  const float* pos_cos     = (const float*)d_in[1];
  const float* pos_sin     = (const float*)d_in[2];
  const int*   memory_bank = (const int*)  d_in[3];
  const float* tok_emb     = (const float*)d_in[4];
  const float* wq          = (const float*)d_in[5];
  const float* wk          = (const float*)d_in[6];
  const float* wv          = (const float*)d_in[7];
  const float* wo          = (const float*)d_in[8];
  const float* attn_norm_w = (const float*)d_in[9];
  const float* mem_norm_w  = (const float*)d_in[10];
  const float* w_gate      = (const float*)d_in[11];
  const float* wg_fuse     = (const float*)d_in[12];
  const float* bg_fuse     = (const float*)d_in[13];
  const float* wm_fuse     = (const float*)d_in[14];
  const float* bm_fuse     = (const float*)d_in[15];
  const float* gumbel_u    = (const float*)d_in[16];
  float* out = (float*)d_out;

  char* ws = (char*)d_ws;
  const size_t U = (size_t)Mn*Dn*sizeof(float);   // 8 MB per unit
  float* hn      = (float*)(ws);          // unit 0; reused: attn_pv
  float* qb      = (float*)(ws + 1*U);    // unit 1; reused: gbuf
  float* kb      = (float*)(ws + 2*U);    // unit 2; reused: topi, then mbuf
  float* vb      = (float*)(ws + 3*U);    // unit 3; reused: topv
  float* h_attn  = (float*)(ws + 4*U);    // unit 4
  float* hbuf    = (float*)(ws + 5*U);    // unit 5
  float* cat     = (float*)(ws + 6*U);    // units 6-7: (4096,1024): [hm | sel_mem]
  int*   cand    = (int*)  (ws + 8*U);            // 64 KB
  float* losses  = (float*)(ws + 8*U + 65536);    // 8 B
  float* attn_pv = hn;
  float* topv    = vb;
  int*   topi    = (int*)kb;
  float* gbuf    = qb;
  float* mbuf    = kb;

  hipMemsetAsync(losses, 0, 2*sizeof(float), stream);

  rmsnorm_kernel<<<Mn, 256, 0, stream>>>(x, attn_norm_w, hn);

  dim3 g64(Dn/64, Mn/64);   // (8, 64)
  gemm_qkv_kernel<<<g64, 256, 0, stream>>>(hn, wq, pos_cos, pos_sin, qb, 1);
  gemm_qkv_kernel<<<g64, 256, 0, stream>>>(hn, wk, pos_cos, pos_sin, kb, 1);
  gemm_qkv_kernel<<<g64, 256, 0, stream>>>(hn, wv, pos_cos, pos_sin, vb, 0);

  attn_kernel<<<dim3(Sn/64, Bn*NHn), 256, 0, stream>>>(qb, kb, vb, attn_pv);

  gemm_f32_kernel<<<g64, 256, 0, stream>>>(attn_pv, wo, h_attn, 512, 512);

  h_hm_kernel<<<Mn, 256, 0, stream>>>(x, h_attn, mem_norm_w, hbuf, cat);

  logits_topk_kernel<<<dim3(KNn/128, Mn/128), 256, 0, stream>>>(cat, w_gate, topv, topi);
  merge_topk_kernel<<<Mn/4, 256, 0, stream>>>(topv, topi, cand);

  select_kernel<<<Mn, 256, 0, stream>>>(cat, cand, memory_bank, tok_emb, gumbel_u, cat, losses);

  gemm_f32_kernel<<<g64, 256, 0, stream>>>(cat, wg_fuse, gbuf, 1024, 512);
  gemm_f32_kernel<<<g64, 256, 0, stream>>>(cat, wm_fuse, mbuf, 1024, 512);

  final_kernel<<<(Mn*Dn)/256, 256, 0, stream>>>(hbuf, gbuf, mbuf, bg_fuse, bm_fuse, losses, out);
}

// Round 2
// 1596.204 us; speedup vs baseline: 24.5550x; 24.5550x over previous
//
#include <hip/hip_runtime.h>
#include <math.h>

#define Bn 4
#define Sn 1024
#define Dn 512
#define NHn 8
#define HDn 64
#define KNn 16384
#define KLn 8
#define NCn 4
#define Mn (Bn*Sn)   // 4096 rows

// ---------------- helpers ----------------

__device__ __forceinline__ float wred_sum(float v){
  #pragma unroll
  for (int m=1;m<64;m<<=1) v += __shfl_xor(v, m, 64);
  return v;
}

// total order: value desc, index asc (matches jax.lax.top_k tie-break)
__device__ __forceinline__ bool better(float v, int i, float v2, int i2){
  return (v>v2) || (v==v2 && i<i2);
}

// compare-exchange: keep the better (v,i) in (va,ia)
__device__ __forceinline__ void cex(float& va, int& ia, float& vb, int& ib){
  if (!better(va,ia,vb,ib)){
    float tv=va; va=vb; vb=tv;
    int   ti=ia; ia=ib; ib=ti;
  }
}

// insert one (v,gi) into a sorted-desc top4 held in named scalars
__device__ __forceinline__ void ins4(float v, int gi,
                                     float&a0,int&x0,float&a1,int&x1,
                                     float&a2,int&x2,float&a3,int&x3){
  if (better(v,gi,a3,x3)){
    a3=v; x3=gi;
    cex(a2,x2,a3,x3); cex(a1,x1,a2,x2); cex(a0,x0,a1,x1);
  }
}

// merge a sorted-desc 4-list (a) with another sorted-desc 4-list (b):
// bitonic: [a0..a3, b3..b0] -> split -> sort top half. Result in a, sorted desc.
__device__ __forceinline__ void merge4(float&a0,int&x0,float&a1,int&x1,
                                       float&a2,int&x2,float&a3,int&x3,
                                       float b0,int y0,float b1,int y1,
                                       float b2,int y2,float b3,int y3){
  cex(a0,x0,b3,y3); cex(a1,x1,b2,y2); cex(a2,x2,b1,y1); cex(a3,x3,b0,y0);
  cex(a0,x0,a2,x2); cex(a1,x1,a3,x3);
  cex(a0,x0,a1,x1); cex(a2,x2,a3,x3);
}

// ---------------- 1. RMSNorm(x) -> hn ----------------

__global__ __launch_bounds__(256) void rmsnorm_kernel(const float* __restrict__ x,
                                                      const float* __restrict__ w,
                                                      float* __restrict__ y){
  int row = blockIdx.x, tid = threadIdx.x;
  const float2* xr = (const float2*)(x + (size_t)row*Dn);
  float2 v = xr[tid];
  float ss = v.x*v.x + v.y*v.y;
  ss = wred_sum(ss);
  __shared__ float red[4];
  int wid = tid>>6, lane = tid&63;
  if (lane==0) red[wid]=ss;
  __syncthreads();
  float tot = red[0]+red[1]+red[2]+red[3];
  float sc = rsqrtf(tot*(1.0f/Dn) + 1e-5f);
  float2 wv = ((const float2*)w)[tid];
  ((float2*)(y + (size_t)row*Dn))[tid] = make_float2(v.x*sc*wv.x, v.y*sc*wv.y);
}

// ------------- 2. QKV GEMM (+RoPE) with relayout to (B,NH,S,HD) -------------

__global__ __launch_bounds__(256) void gemm_qkv_kernel(const float* __restrict__ A,
                                                       const float* __restrict__ Bw,
                                                       const float* __restrict__ pc,
                                                       const float* __restrict__ ps,
                                                       float* __restrict__ out, int rope){
  __shared__ float As[16][68];
  __shared__ float Bs[16][68];
  int tid=threadIdx.x, tx=tid&15, ty=tid>>4;
  int n0 = blockIdx.x*64, m0 = blockIdx.y*64;
  float acc[4][4] = {};
  for (int kt=0; kt<Dn; kt+=16){
    #pragma unroll
    for (int t=0;t<4;t++){ int i=tid+t*256; int r=i>>4, c=i&15; As[c][r]=A[(size_t)(m0+r)*Dn + kt+c]; }
    #pragma unroll
    for (int t=0;t<4;t++){ int i=tid+t*256; int r=i>>6, c=i&63; Bs[r][c]=Bw[(size_t)(kt+r)*Dn + n0+c]; }
    __syncthreads();
    #pragma unroll
    for (int kk=0;kk<16;kk++){
      float a[4], b[4];
      #pragma unroll
      for (int i=0;i<4;i++) a[i]=As[kk][ty*4+i];
      #pragma unroll
      for (int j=0;j<4;j++) b[j]=Bs[kk][tx*4+j];
      #pragma unroll
      for (int i=0;i<4;i++)
        #pragma unroll
        for (int j=0;j<4;j++) acc[i][j] += a[i]*b[j];
    }
    __syncthreads();
  }
  #pragma unroll
  for (int i=0;i<4;i++){
    int mm = m0+ty*4+i; int b = mm>>10; int s = mm&1023;
    #pragma unroll
    for (int j=0;j<4;j+=2){
      int n = n0+tx*4+j; int h = n>>6; int d = n&63;
      size_t o = ((size_t)(b*NHn+h)*Sn + s)*HDn + d;
      float a0=acc[i][j], a1=acc[i][j+1];
      if (rope){
        float c = pc[s*32 + (d>>1)], sn = ps[s*32 + (d>>1)];
        out[o]   = a0*c - a1*sn;
        out[o+1] = a0*sn + a1*c;
      } else { out[o]=a0; out[o+1]=a1; }
    }
  }
}

// ---------------- generic f32 GEMM: C = A(MxK) @ B(KxN), row-major ----------------

__global__ __launch_bounds__(256) void gemm_f32_kernel(const float* __restrict__ A,
                                                       const float* __restrict__ Bw,
                                                       float* __restrict__ C, int K, int N){
  __shared__ float As[16][68];
  __shared__ float Bs[16][68];
  int tid=threadIdx.x, tx=tid&15, ty=tid>>4;
  int n0 = blockIdx.x*64, m0 = blockIdx.y*64;
  float acc[4][4] = {};
  for (int kt=0; kt<K; kt+=16){
    #pragma unroll
    for (int t=0;t<4;t++){ int i=tid+t*256; int r=i>>4, c=i&15; As[c][r]=A[(size_t)(m0+r)*K + kt+c]; }
    #pragma unroll
    for (int t=0;t<4;t++){ int i=tid+t*256; int r=i>>6, c=i&63; Bs[r][c]=Bw[(size_t)(kt+r)*N + n0+c]; }
    __syncthreads();
    #pragma unroll
    for (int kk=0;kk<16;kk++){
      float a[4], b[4];
      #pragma unroll
      for (int i=0;i<4;i++) a[i]=As[kk][ty*4+i];
      #pragma unroll
      for (int j=0;j<4;j++) b[j]=Bs[kk][tx*4+j];
      #pragma unroll
      for (int i=0;i<4;i++)
        #pragma unroll
        for (int j=0;j<4;j++) acc[i][j] += a[i]*b[j];
    }
    __syncthreads();
  }
  #pragma unroll
  for (int i=0;i<4;i++)
    #pragma unroll
    for (int j=0;j<4;j++)
      C[(size_t)(m0+ty*4+i)*N + n0+tx*4+j] = acc[i][j];
}

// ---------------- 3. causal flash attention, f32, 64x64 tiles ----------------

__global__ __launch_bounds__(256) void attn_kernel(const float* __restrict__ q,
                                                   const float* __restrict__ k,
                                                   const float* __restrict__ v,
                                                   float* __restrict__ o){
  __shared__ float Qs[64][65];
  __shared__ float KPs[64][65];
  __shared__ float Vs[64][65];
  __shared__ float mArr[64], lArr[64], aArr[64];
  int tid=threadIdx.x, tx=tid&15, ty=tid>>4;
  int qt=blockIdx.x, bh=blockIdx.y;
  const float* Qp = q + (size_t)bh*Sn*HDn + (size_t)qt*64*HDn;
  const float* Kp = k + (size_t)bh*Sn*HDn;
  const float* Vp = v + (size_t)bh*Sn*HDn;
  #pragma unroll
  for (int t=0;t<16;t++){ int i=tid+t*256; int r=i>>6, c=i&63; Qs[r][c]=Qp[(size_t)r*64+c]; }
  if (tid<64){ mArr[tid]=-1e30f; lArr[tid]=0.f; }
  float O[4][4] = {};
  __syncthreads();
  for (int kt=0; kt<=qt; kt++){
    #pragma unroll
    for (int t=0;t<16;t++){
      int i=tid+t*256; int r=i>>6, c=i&63;
      KPs[r][c]=Kp[(size_t)(kt*64+r)*64+c];
      Vs[r][c] =Vp[(size_t)(kt*64+r)*64+c];
    }
    __syncthreads();
    float sc[4][4] = {};
    #pragma unroll 8
    for (int d=0; d<64; d++){
      float a[4], b[4];
      #pragma unroll
      for (int i=0;i<4;i++) a[i]=Qs[ty*4+i][d];
      #pragma unroll
      for (int j=0;j<4;j++) b[j]=KPs[tx*4+j][d];
      #pragma unroll
      for (int i=0;i<4;i++)
        #pragma unroll
        for (int j=0;j<4;j++) sc[i][j] += a[i]*b[j];
    }
    __syncthreads();
    #pragma unroll
    for (int i=0;i<4;i++){
      int qg = qt*64+ty*4+i;
      #pragma unroll
      for (int j=0;j<4;j++){
        int kg = kt*64+tx*4+j;
        KPs[ty*4+i][tx*4+j] = (kg<=qg) ? sc[i][j]*0.125f : -1e9f;
      }
    }
    __syncthreads();
    if (tid<64){
      int r=tid;
      float mt=-1e30f;
      for (int c=0;c<64;c++) mt=fmaxf(mt, KPs[r][c]);
      float mn = fmaxf(mArr[r], mt);
      float al = __expf(mArr[r]-mn);
      float sum=0.f;
      for (int c=0;c<64;c++){ float p=__expf(KPs[r][c]-mn); KPs[r][c]=p; sum+=p; }
      lArr[r]=lArr[r]*al+sum; mArr[r]=mn; aArr[r]=al;
    }
    __syncthreads();
    #pragma unroll
    for (int i=0;i<4;i++){ float al=aArr[ty*4+i];
      #pragma unroll
      for (int j=0;j<4;j++) O[i][j]*=al; }
    #pragma unroll 8
    for (int kk=0; kk<64; kk++){
      float p[4], vv[4];
      #pragma unroll
      for (int i=0;i<4;i++) p[i]=KPs[ty*4+i][kk];
      #pragma unroll
      for (int j=0;j<4;j++) vv[j]=Vs[kk][tx*4+j];
      #pragma unroll
      for (int i=0;i<4;i++)
        #pragma unroll
        for (int j=0;j<4;j++) O[i][j] += p[i]*vv[j];
    }
    __syncthreads();
  }
  int b=bh>>3, h=bh&7;
  #pragma unroll
  for (int i=0;i<4;i++){
    int qg = qt*64+ty*4+i;
    float inv = 1.f/lArr[ty*4+i];
    #pragma unroll
    for (int j=0;j<4;j++)
      o[((size_t)(b*Sn+qg))*Dn + h*HDn + tx*4+j] = O[i][j]*inv;
  }
}

// ---------------- 5. h = x + h_attn ; hm = rms(h_attn)*w -> cat[:, :512] ----------------

__global__ __launch_bounds__(256) void h_hm_kernel(const float* __restrict__ x,
                                                   const float* __restrict__ ha,
                                                   const float* __restrict__ w,
                                                   float* __restrict__ h,
                                                   float* __restrict__ cat){
  int row=blockIdx.x, tid=threadIdx.x;
  float2 a = ((const float2*)(ha + (size_t)row*Dn))[tid];
  float2 xv = ((const float2*)(x + (size_t)row*Dn))[tid];
  float ss = a.x*a.x + a.y*a.y;
  ss = wred_sum(ss);
  __shared__ float red[4];
  int wid=tid>>6, lane=tid&63;
  if (lane==0) red[wid]=ss;
  __syncthreads();
  float tot = red[0]+red[1]+red[2]+red[3];
  float sc = rsqrtf(tot*(1.0f/Dn) + 1e-5f);
  float2 wv = ((const float2*)w)[tid];
  ((float2*)(h + (size_t)row*Dn))[tid] = make_float2(xv.x+a.x, xv.y+a.y);
  ((float2*)(cat + (size_t)row*1024))[tid] = make_float2(a.x*sc*wv.x, a.y*sc*wv.y);
}

// ---------------- 6. logits GEMM (128x128 tile, 8x8/thread) + fused per-tile top4 ----------------
// Epilogue is a compile-time-indexed bitonic top-4 merge (NO runtime array indexing:
// runtime-indexed regs demote the accumulator to scratch -> 200 GB of HBM traffic).

__global__ __launch_bounds__(256) void logits_topk_kernel(const float* __restrict__ A,
                                                          const float* __restrict__ Bg,
                                                          float* __restrict__ topv,
                                                          int* __restrict__ topi){
  __shared__ float As[16][136];
  __shared__ float Bs[16][136];
  int tid=threadIdx.x, tx=tid&15, ty=tid>>4;
  int n0 = blockIdx.x*128, m0 = blockIdx.y*128;
  float acc[8][8] = {};
  for (int kt=0; kt<Dn; kt+=16){
    #pragma unroll
    for (int t=0;t<8;t++){ int i=tid+t*256; int r=i>>4, c=i&15; As[c][r]=A[(size_t)(m0+r)*1024 + kt+c]; }
    #pragma unroll
    for (int t=0;t<8;t++){ int i=tid+t*256; int r=i>>7, c=i&127; Bs[r][c]=Bg[(size_t)(kt+r)*KNn + n0+c]; }
    __syncthreads();
    #pragma unroll
    for (int kk=0;kk<16;kk++){
      float4 a0 = *(const float4*)&As[kk][ty*8];
      float4 a1 = *(const float4*)&As[kk][ty*8+4];
      float4 b0 = *(const float4*)&Bs[kk][tx*8];
      float4 b1 = *(const float4*)&Bs[kk][tx*8+4];
      float a[8]={a0.x,a0.y,a0.z,a0.w,a1.x,a1.y,a1.z,a1.w};
      float b[8]={b0.x,b0.y,b0.z,b0.w,b1.x,b1.y,b1.z,b1.w};
      #pragma unroll
      for (int i=0;i<8;i++)
        #pragma unroll
        for (int j=0;j<8;j++) acc[i][j] += a[i]*b[j];
    }
    __syncthreads();
  }
  // per-row top-4 within this 128-col tile; 16 tx-lanes collaborate per row
  #pragma unroll
  for (int i=0;i<8;i++){
    int row = m0 + ty*8 + i;
    float a0=-INFINITY,a1=-INFINITY,a2=-INFINITY,a3=-INFINITY;
    int   x0=0x7fffffff,x1=0x7fffffff,x2=0x7fffffff,x3=0x7fffffff;
    #pragma unroll
    for (int j=0;j<8;j++) ins4(acc[i][j], n0+tx*8+j, a0,x0,a1,x1,a2,x2,a3,x3);
    #pragma unroll
    for (int mask=1; mask<16; mask<<=1){
      float b0=__shfl_xor(a0,mask,16), b1=__shfl_xor(a1,mask,16);
      float b2=__shfl_xor(a2,mask,16), b3=__shfl_xor(a3,mask,16);
      int   y0=__shfl_xor(x0,mask,16), y1=__shfl_xor(x1,mask,16);
      int   y2=__shfl_xor(x2,mask,16), y3=__shfl_xor(x3,mask,16);
      merge4(a0,x0,a1,x1,a2,x2,a3,x3, b0,y0,b1,y1,b2,y2,b3,y3);
    }
    if (tx==0){
      size_t base = ((size_t)row*128 + blockIdx.x)*4;
      topv[base+0]=a0; topv[base+1]=a1; topv[base+2]=a2; topv[base+3]=a3;
      topi[base+0]=x0; topi[base+1]=x1; topi[base+2]=x2; topi[base+3]=x3;
    }
  }
}

// ---------------- 7. merge 128 tile-partials -> global top4 (sorted desc) ----------------

__global__ __launch_bounds__(256) void merge_topk_kernel(const float* __restrict__ topv,
                                                         const int* __restrict__ topi,
                                                         int* __restrict__ cand){
  int tid=threadIdx.x, wid=tid>>6, lane=tid&63;
  int row = blockIdx.x*4 + wid;
  size_t base = (size_t)row*512 + (size_t)lane*8;
  // two sorted 4-lists per lane
  float a0=topv[base+0],a1=topv[base+1],a2=topv[base+2],a3=topv[base+3];
  int   x0=topi[base+0],x1=topi[base+1],x2=topi[base+2],x3=topi[base+3];
  float b0=topv[base+4],b1=topv[base+5],b2=topv[base+6],b3=topv[base+7];
  int   y0=topi[base+4],y1=topi[base+5],y2=topi[base+6],y3=topi[base+7];
  merge4(a0,x0,a1,x1,a2,x2,a3,x3, b0,y0,b1,y1,b2,y2,b3,y3);
  #pragma unroll
  for (int mask=1; mask<64; mask<<=1){
    float c0=__shfl_xor(a0,mask,64), c1=__shfl_xor(a1,mask,64);
    float c2=__shfl_xor(a2,mask,64), c3=__shfl_xor(a3,mask,64);
    int   z0=__shfl_xor(x0,mask,64), z1=__shfl_xor(x1,mask,64);
    int   z2=__shfl_xor(x2,mask,64), z3=__shfl_xor(x3,mask,64);
    merge4(a0,x0,a1,x1,a2,x2,a3,x3, c0,z0,c1,z1,c2,z2,c3,z3);
  }
  if (lane==0){
    cand[(size_t)row*4+0]=x0; cand[(size_t)row*4+1]=x1;
    cand[(size_t)row*4+2]=x2; cand[(size_t)row*4+3]=x3;
  }
}

// ------- 8. gather cand_mem, sim, gumbel select, losses, write sel_mem -> cat[:,512:] -------

__global__ __launch_bounds__(256) void select_kernel(const float* __restrict__ cat,
                                                     const int* __restrict__ cand,
                                                     const int* __restrict__ mem_bank,
                                                     const float* __restrict__ tok_emb,
                                                     const float* __restrict__ gu,
                                                     float* __restrict__ cat_out,
                                                     float* __restrict__ losses){
  __shared__ float cm[4][512];
  __shared__ int ids[32];
  __shared__ float wred[15][4];
  __shared__ int sel_s;
  int row=blockIdx.x, tid=threadIdx.x;
  if (tid<32) ids[tid] = mem_bank[(size_t)cand[(size_t)row*4 + (tid>>3)]*KLn + (tid&7)];
  __syncthreads();
  #pragma unroll
  for (int n=0;n<4;n++){
    float s0=0.f, s1=0.f;
    #pragma unroll
    for (int l=0;l<8;l++){
      const float* e = tok_emb + (size_t)ids[n*8+l]*Dn;
      s0 += e[tid]; s1 += e[tid+256];
    }
    cm[n][tid]=s0*0.125f; cm[n][tid+256]=s1*0.125f;
  }
  __syncthreads();
  float hm0 = cat[(size_t)row*1024 + tid], hm1 = cat[(size_t)row*1024 + 256 + tid];
  float c0[4], c1[4];
  #pragma unroll
  for (int n=0;n<4;n++){ c0[n]=cm[n][tid]; c1[n]=cm[n][tid+256]; }
  float p[15];
  p[0]=hm0*hm0+hm1*hm1;
  #pragma unroll
  for (int n=0;n<4;n++) p[1+n]=hm0*c0[n]+hm1*c1[n];
  int qi=5;
  #pragma unroll
  for (int n=0;n<4;n++)
    #pragma unroll
    for (int m=n;m<4;m++) p[qi++]=c0[n]*c0[m]+c1[n]*c1[m];
  int wid=tid>>6, lane=tid&63;
  #pragma unroll
  for (int i=0;i<15;i++) p[i]=wred_sum(p[i]);
  if (lane==0){
    #pragma unroll
    for (int i=0;i<15;i++) wred[i][wid]=p[i];
  }
  __syncthreads();
  if (tid==0){
    float tot[15];
    #pragma unroll
    for (int i=0;i<15;i++) tot[i]=wred[i][0]+wred[i][1]+wred[i][2]+wred[i][3];
    float hn2 = fmaxf(sqrtf(tot[0]), 1e-8f);
    const int diag[4]={5,9,12,14};
    float sim[4], dn[4];
    #pragma unroll
    for (int n=0;n<4;n++){
      float cn = sqrtf(tot[diag[n]]);
      sim[n] = tot[1+n]/(hn2*fmaxf(cn,1e-8f));
      dn[n]  = fmaxf(cn,1e-12f);
    }
    float best=-1e30f; int sel=0;
    #pragma unroll
    for (int n=0;n<4;n++){
      float u = gu[(size_t)row*4+n];
      float g = -logf(-logf(u + 1e-20f) + 1e-20f);
      float a = sim[n]+g;
      if (a>best){ best=a; sel=n; }
    }
    atomicAdd(&losses[0], sim[sel]);
    const int cross[6]={6,7,8,10,11,13};
    const int cn_[6]={0,0,0,1,1,2}, cm_[6]={1,2,3,2,3,3};
    float dv=0.f;
    #pragma unroll
    for (int t=0;t<6;t++) dv += 2.f*tot[cross[t]]/(dn[cn_[t]]*dn[cm_[t]]);
    atomicAdd(&losses[1], dv);
    sel_s=sel;
  }
  __syncthreads();
  int sel=sel_s;
  cat_out[(size_t)row*1024 + 512 + tid]       = cm[sel][tid];
  cat_out[(size_t)row*1024 + 512 + 256 + tid] = cm[sel][tid+256];
}

// ---------------- 12. out = h + sigmoid(g+bg)*(m+bm); losses tail ----------------

__global__ __launch_bounds__(256) void final_kernel(const float* __restrict__ h,
                                                    const float* __restrict__ g,
                                                    const float* __restrict__ m,
                                                    const float* __restrict__ bg,
                                                    const float* __restrict__ bm,
                                                    const float* __restrict__ losses,
                                                    float* __restrict__ out){
  int idx = blockIdx.x*256 + threadIdx.x;
  int n = idx & (Dn-1);
  float gl = g[idx] + bg[n];
  float ml = m[idx] + bm[n];
  float gate = 1.f/(1.f+__expf(-gl));
  out[idx] = h[idx] + gate*ml;
  if (idx==0){
    out[(size_t)Mn*Dn]     = -losses[0]*(1.f/(float)Mn);
    out[(size_t)Mn*Dn + 1] =  losses[1]*(1.f/(float)(Mn*NCn*(NCn-1)));
  }
}

// ---------------- launch ----------------

extern "C" void kernel_launch(void* const* d_in, const int* in_sizes, int n_in,
                              void* d_out, int out_size, void* d_ws, size_t ws_size,
                              hipStream_t stream){
  const float* x           = (const float*)d_in[0];
  const float* pos_cos     = (const float*)d_in[1];
  const float* pos_sin     = (const float*)d_in[2];
  const int*   memory_bank = (const int*)  d_in[3];
  const float* tok_emb     = (const float*)d_in[4];
  const float* wq          = (const float*)d_in[5];
  const float* wk          = (const float*)d_in[6];
  const float* wv          = (const float*)d_in[7];
  const float* wo          = (const float*)d_in[8];
  const float* attn_norm_w = (const float*)d_in[9];
  const float* mem_norm_w  = (const float*)d_in[10];
  const float* w_gate      = (const float*)d_in[11];
  const float* wg_fuse     = (const float*)d_in[12];
  const float* bg_fuse     = (const float*)d_in[13];
  const float* wm_fuse     = (const float*)d_in[14];
  const float* bm_fuse     = (const float*)d_in[15];
  const float* gumbel_u    = (const float*)d_in[16];
  float* out = (float*)d_out;

  char* ws = (char*)d_ws;
  const size_t U = (size_t)Mn*Dn*sizeof(float);   // 8 MB per unit
  float* hn      = (float*)(ws);          // unit 0; reused: attn_pv
  float* qb      = (float*)(ws + 1*U);    // unit 1; reused: gbuf
  float* kb      = (float*)(ws + 2*U);    // unit 2; reused: topi, then mbuf
  float* vb      = (float*)(ws + 3*U);    // unit 3; reused: topv
  float* h_attn  = (float*)(ws + 4*U);    // unit 4
  float* hbuf    = (float*)(ws + 5*U);    // unit 5
  float* cat     = (float*)(ws + 6*U);    // units 6-7: (4096,1024): [hm | sel_mem]
  int*   cand    = (int*)  (ws + 8*U);            // 64 KB
  float* losses  = (float*)(ws + 8*U + 65536);    // 8 B
  float* attn_pv = hn;
  float* topv    = vb;
  int*   topi    = (int*)kb;
  float* gbuf    = qb;
  float* mbuf    = kb;

  hipMemsetAsync(losses, 0, 2*sizeof(float), stream);

  rmsnorm_kernel<<<Mn, 256, 0, stream>>>(x, attn_norm_w, hn);

  dim3 g64(Dn/64, Mn/64);   // (8, 64)
  gemm_qkv_kernel<<<g64, 256, 0, stream>>>(hn, wq, pos_cos, pos_sin, qb, 1);
  gemm_qkv_kernel<<<g64, 256, 0, stream>>>(hn, wk, pos_cos, pos_sin, kb, 1);
  gemm_qkv_kernel<<<g64, 256, 0, stream>>>(hn, wv, pos_cos, pos_sin, vb, 0);

  attn_kernel<<<dim3(Sn/64, Bn*NHn), 256, 0, stream>>>(qb, kb, vb, attn_pv);

  gemm_f32_kernel<<<g64, 256, 0, stream>>>(attn_pv, wo, h_attn, 512, 512);

  h_hm_kernel<<<Mn, 256, 0, stream>>>(x, h_attn, mem_norm_w, hbuf, cat);

  logits_topk_kernel<<<dim3(KNn/128, Mn/128), 256, 0, stream>>>(cat, w_gate, topv, topi);
  merge_topk_kernel<<<Mn/4, 256, 0, stream>>>(topv, topi, cand);

  select_kernel<<<Mn, 256, 0, stream>>>(cat, cand, memory_bank, tok_emb, gumbel_u, cat, losses);

  gemm_f32_kernel<<<g64, 256, 0, stream>>>(cat, wg_fuse, gbuf, 1024, 512);
  gemm_f32_kernel<<<g64, 256, 0, stream>>>(cat, wm_fuse, mbuf, 1024, 512);

  final_kernel<<<(Mn*Dn)/256, 256, 0, stream>>>(hbuf, gbuf, mbuf, bg_fuse, bm_fuse, losses, out);
}

// Round 4
// 1098.161 us; speedup vs baseline: 35.6913x; 1.4535x over previous
//
#include <hip/hip_runtime.h>
#include <hip/hip_bf16.h>
#include <math.h>

#define Bn 4
#define Sn 1024
#define Dn 512
#define NHn 8
#define HDn 64
#define KNn 16384
#define KLn 8
#define NCn 4
#define Mn (Bn*Sn)   // 4096 rows

typedef __attribute__((ext_vector_type(8))) short short8;
typedef __attribute__((ext_vector_type(4))) float f32x4;

// ---------------- helpers ----------------

__device__ __forceinline__ float wred_sum(float v){
  #pragma unroll
  for (int m=1;m<64;m<<=1) v += __shfl_xor(v, m, 64);
  return v;
}

// total order: value desc, index asc (matches jax.lax.top_k tie-break)
__device__ __forceinline__ bool better(float v, int i, float v2, int i2){
  return (v>v2) || (v==v2 && i<i2);
}

__device__ __forceinline__ void cex(float& va, int& ia, float& vb, int& ib){
  if (!better(va,ia,vb,ib)){
    float tv=va; va=vb; vb=tv;
    int   ti=ia; ia=ib; ib=ti;
  }
}

__device__ __forceinline__ void ins4(float v, int gi,
                                     float&a0,int&x0,float&a1,int&x1,
                                     float&a2,int&x2,float&a3,int&x3){
  if (better(v,gi,a3,x3)){
    a3=v; x3=gi;
    cex(a2,x2,a3,x3); cex(a1,x1,a2,x2); cex(a0,x0,a1,x1);
  }
}

// merge sorted-desc 4-list a with sorted-desc 4-list b -> a
__device__ __forceinline__ void merge4(float&a0,int&x0,float&a1,int&x1,
                                       float&a2,int&x2,float&a3,int&x3,
                                       float b0,int y0,float b1,int y1,
                                       float b2,int y2,float b3,int y3){
  cex(a0,x0,b3,y3); cex(a1,x1,b2,y2); cex(a2,x2,b1,y1); cex(a3,x3,b0,y0);
  cex(a0,x0,a2,x2); cex(a1,x1,a3,x3);
  cex(a0,x0,a1,x1); cex(a2,x2,a3,x3);
}

__device__ __forceinline__ ushort f2bf(float f){
  __hip_bfloat16 h = __float2bfloat16(f);
  return __builtin_bit_cast(ushort, h);
}

// ---------------- 1. RMSNorm(x) -> hn ----------------

__global__ __launch_bounds__(256) void rmsnorm_kernel(const float* __restrict__ x,
                                                      const float* __restrict__ w,
                                                      float* __restrict__ y){
  int row = blockIdx.x, tid = threadIdx.x;
  const float2* xr = (const float2*)(x + (size_t)row*Dn);
  float2 v = xr[tid];
  float ss = v.x*v.x + v.y*v.y;
  ss = wred_sum(ss);
  __shared__ float red[4];
  int wid = tid>>6, lane = tid&63;
  if (lane==0) red[wid]=ss;
  __syncthreads();
  float tot = red[0]+red[1]+red[2]+red[3];
  float sc = rsqrtf(tot*(1.0f/Dn) + 1e-5f);
  float2 wv = ((const float2*)w)[tid];
  ((float2*)(y + (size_t)row*Dn))[tid] = make_float2(v.x*sc*wv.x, v.y*sc*wv.y);
}

// ------------- 2. QKV GEMM (+RoPE) with relayout to (B,NH,S,HD) -------------

__global__ __launch_bounds__(256) void gemm_qkv_kernel(const float* __restrict__ A,
                                                       const float* __restrict__ Bw,
                                                       const float* __restrict__ pc,
                                                       const float* __restrict__ ps,
                                                       float* __restrict__ out, int rope){
  __shared__ float As[16][68];
  __shared__ float Bs[16][68];
  int tid=threadIdx.x, tx=tid&15, ty=tid>>4;
  int n0 = blockIdx.x*64, m0 = blockIdx.y*64;
  float acc[4][4] = {};
  for (int kt=0; kt<Dn; kt+=16){
    #pragma unroll
    for (int t=0;t<4;t++){ int i=tid+t*256; int r=i>>4, c=i&15; As[c][r]=A[(size_t)(m0+r)*Dn + kt+c]; }
    #pragma unroll
    for (int t=0;t<4;t++){ int i=tid+t*256; int r=i>>6, c=i&63; Bs[r][c]=Bw[(size_t)(kt+r)*Dn + n0+c]; }
    __syncthreads();
    #pragma unroll
    for (int kk=0;kk<16;kk++){
      float a[4], b[4];
      #pragma unroll
      for (int i=0;i<4;i++) a[i]=As[kk][ty*4+i];
      #pragma unroll
      for (int j=0;j<4;j++) b[j]=Bs[kk][tx*4+j];
      #pragma unroll
      for (int i=0;i<4;i++)
        #pragma unroll
        for (int j=0;j<4;j++) acc[i][j] += a[i]*b[j];
    }
    __syncthreads();
  }
  #pragma unroll
  for (int i=0;i<4;i++){
    int mm = m0+ty*4+i; int b = mm>>10; int s = mm&1023;
    #pragma unroll
    for (int j=0;j<4;j+=2){
      int n = n0+tx*4+j; int h = n>>6; int d = n&63;
      size_t o = ((size_t)(b*NHn+h)*Sn + s)*HDn + d;
      float a0=acc[i][j], a1=acc[i][j+1];
      if (rope){
        float c = pc[s*32 + (d>>1)], sn = ps[s*32 + (d>>1)];
        out[o]   = a0*c - a1*sn;
        out[o+1] = a0*sn + a1*c;
      } else { out[o]=a0; out[o+1]=a1; }
    }
  }
}

// ---------------- generic f32 GEMM: C = A(MxK) @ B(KxN), row-major ----------------

__global__ __launch_bounds__(256) void gemm_f32_kernel(const float* __restrict__ A,
                                                       const float* __restrict__ Bw,
                                                       float* __restrict__ C, int K, int N){
  __shared__ float As[16][68];
  __shared__ float Bs[16][68];
  int tid=threadIdx.x, tx=tid&15, ty=tid>>4;
  int n0 = blockIdx.x*64, m0 = blockIdx.y*64;
  float acc[4][4] = {};
  for (int kt=0; kt<K; kt+=16){
    #pragma unroll
    for (int t=0;t<4;t++){ int i=tid+t*256; int r=i>>4, c=i&15; As[c][r]=A[(size_t)(m0+r)*K + kt+c]; }
    #pragma unroll
    for (int t=0;t<4;t++){ int i=tid+t*256; int r=i>>6, c=i&63; Bs[r][c]=Bw[(size_t)(kt+r)*N + n0+c]; }
    __syncthreads();
    #pragma unroll
    for (int kk=0;kk<16;kk++){
      float a[4], b[4];
      #pragma unroll
      for (int i=0;i<4;i++) a[i]=As[kk][ty*4+i];
      #pragma unroll
      for (int j=0;j<4;j++) b[j]=Bs[kk][tx*4+j];
      #pragma unroll
      for (int i=0;i<4;i++)
        #pragma unroll
        for (int j=0;j<4;j++) acc[i][j] += a[i]*b[j];
    }
    __syncthreads();
  }
  #pragma unroll
  for (int i=0;i<4;i++)
    #pragma unroll
    for (int j=0;j<4;j++)
      C[(size_t)(m0+ty*4+i)*N + n0+tx*4+j] = acc[i][j];
}

// ---------------- 3. causal flash attention, f32, 64x64 tiles ----------------

__global__ __launch_bounds__(256) void attn_kernel(const float* __restrict__ q,
                                                   const float* __restrict__ k,
                                                   const float* __restrict__ v,
                                                   float* __restrict__ o){
  __shared__ float Qs[64][65];
  __shared__ float KPs[64][65];
  __shared__ float Vs[64][65];
  __shared__ float mArr[64], lArr[64], aArr[64];
  int tid=threadIdx.x, tx=tid&15, ty=tid>>4;
  int qt=blockIdx.x, bh=blockIdx.y;
  const float* Qp = q + (size_t)bh*Sn*HDn + (size_t)qt*64*HDn;
  const float* Kp = k + (size_t)bh*Sn*HDn;
  const float* Vp = v + (size_t)bh*Sn*HDn;
  #pragma unroll
  for (int t=0;t<16;t++){ int i=tid+t*256; int r=i>>6, c=i&63; Qs[r][c]=Qp[(size_t)r*64+c]; }
  if (tid<64){ mArr[tid]=-1e30f; lArr[tid]=0.f; }
  float O[4][4] = {};
  __syncthreads();
  for (int kt=0; kt<=qt; kt++){
    #pragma unroll
    for (int t=0;t<16;t++){
      int i=tid+t*256; int r=i>>6, c=i&63;
      KPs[r][c]=Kp[(size_t)(kt*64+r)*64+c];
      Vs[r][c] =Vp[(size_t)(kt*64+r)*64+c];
    }
    __syncthreads();
    float sc[4][4] = {};
    #pragma unroll 8
    for (int d=0; d<64; d++){
      float a[4], b[4];
      #pragma unroll
      for (int i=0;i<4;i++) a[i]=Qs[ty*4+i][d];
      #pragma unroll
      for (int j=0;j<4;j++) b[j]=KPs[tx*4+j][d];
      #pragma unroll
      for (int i=0;i<4;i++)
        #pragma unroll
        for (int j=0;j<4;j++) sc[i][j] += a[i]*b[j];
    }
    __syncthreads();
    #pragma unroll
    for (int i=0;i<4;i++){
      int qg = qt*64+ty*4+i;
      #pragma unroll
      for (int j=0;j<4;j++){
        int kg = kt*64+tx*4+j;
        KPs[ty*4+i][tx*4+j] = (kg<=qg) ? sc[i][j]*0.125f : -1e9f;
      }
    }
    __syncthreads();
    // wave-parallel online softmax: 4 lanes per row (consecutive tids -> same wave, lockstep)
    {
      int r = tid>>2, sub = tid&3;
      float mt = -1e30f;
      #pragma unroll
      for (int c=0;c<16;c++) mt = fmaxf(mt, KPs[r][sub*16+c]);
      mt = fmaxf(mt, __shfl_xor(mt,1,64));
      mt = fmaxf(mt, __shfl_xor(mt,2,64));
      float mn = fmaxf(mArr[r], mt);
      float sum = 0.f;
      #pragma unroll
      for (int c=0;c<16;c++){
        float p = __expf(KPs[r][sub*16+c]-mn);
        KPs[r][sub*16+c] = p;
        sum += p;
      }
      sum += __shfl_xor(sum,1,64);
      sum += __shfl_xor(sum,2,64);
      if (sub==0){
        float al = __expf(mArr[r]-mn);
        lArr[r] = lArr[r]*al + sum;
        aArr[r] = al;
        mArr[r] = mn;
      }
    }
    __syncthreads();
    #pragma unroll
    for (int i=0;i<4;i++){ float al=aArr[ty*4+i];
      #pragma unroll
      for (int j=0;j<4;j++) O[i][j]*=al; }
    #pragma unroll 8
    for (int kk=0; kk<64; kk++){
      float p[4], vv[4];
      #pragma unroll
      for (int i=0;i<4;i++) p[i]=KPs[ty*4+i][kk];
      #pragma unroll
      for (int j=0;j<4;j++) vv[j]=Vs[kk][tx*4+j];
      #pragma unroll
      for (int i=0;i<4;i++)
        #pragma unroll
        for (int j=0;j<4;j++) O[i][j] += p[i]*vv[j];
    }
    __syncthreads();
  }
  int b=bh>>3, h=bh&7;
  #pragma unroll
  for (int i=0;i<4;i++){
    int qg = qt*64+ty*4+i;
    float inv = 1.f/lArr[ty*4+i];
    #pragma unroll
    for (int j=0;j<4;j++)
      o[((size_t)(b*Sn+qg))*Dn + h*HDn + tx*4+j] = O[i][j]*inv;
  }
}

// ------- 4. transpose-convert w_gate (512x16384 f32) -> BT (16384x512 bf16) -------

__global__ __launch_bounds__(256) void convert_wgate_kernel(const float* __restrict__ wg,
                                                            ushort* __restrict__ BT){
  __shared__ float T[64][68];
  int tid=threadIdx.x;
  int n0 = blockIdx.x*64, k0 = blockIdx.y*64;
  #pragma unroll
  for (int h=0;h<4;h++){
    int idx = tid + h*256;
    int r = idx>>4, c = (idx&15)*4;     // k-row, n-col
    float4 v = *(const float4*)&wg[(size_t)(k0+r)*KNn + n0+c];
    *(float4*)&T[r][c] = v;
  }
  __syncthreads();
  #pragma unroll
  for (int h=0;h<4;h++){
    int idx = tid + h*256;
    int n = idx>>4, kc = (idx&15)*4;    // n-row of BT, k-col
    ushort4 u;
    u.x = f2bf(T[kc+0][n]);
    u.y = f2bf(T[kc+1][n]);
    u.z = f2bf(T[kc+2][n]);
    u.w = f2bf(T[kc+3][n]);
    *(ushort4*)&BT[(size_t)(n0+n)*Dn + k0+kc] = u;
  }
}

// ---------------- 5. h = x + h_attn ; hm = rms(h_attn)*w -> cat[:, :512] + bf16 copy ----------------

__global__ __launch_bounds__(256) void h_hm_kernel(const float* __restrict__ x,
                                                   const float* __restrict__ ha,
                                                   const float* __restrict__ w,
                                                   float* __restrict__ h,
                                                   float* __restrict__ cat,
                                                   ushort* __restrict__ abf){
  int row=blockIdx.x, tid=threadIdx.x;
  float2 a = ((const float2*)(ha + (size_t)row*Dn))[tid];
  float2 xv = ((const float2*)(x + (size_t)row*Dn))[tid];
  float ss = a.x*a.x + a.y*a.y;
  ss = wred_sum(ss);
  __shared__ float red[4];
  int wid=tid>>6, lane=tid&63;
  if (lane==0) red[wid]=ss;
  __syncthreads();
  float tot = red[0]+red[1]+red[2]+red[3];
  float sc = rsqrtf(tot*(1.0f/Dn) + 1e-5f);
  float2 wv = ((const float2*)w)[tid];
  float hm0 = a.x*sc*wv.x, hm1 = a.y*sc*wv.y;
  ((float2*)(h + (size_t)row*Dn))[tid] = make_float2(xv.x+a.x, xv.y+a.y);
  ((float2*)(cat + (size_t)row*1024))[tid] = make_float2(hm0, hm1);
  ushort2 u; u.x = f2bf(hm0); u.y = f2bf(hm1);
  *(ushort2*)&abf[(size_t)row*Dn + tid*2] = u;
}

// ---------------- 6. bf16 MFMA logits GEMM + fused top-4 ----------------
// A = abf (4096x512 bf16 row-major), BT (16384x512 bf16 row-major; BT[n][k]=w_gate[k][n]).
// 128x128 tile, BK=32, 4 waves in 2x2. mfma_f32_16x16x32_bf16:
//   A-frag: lane holds A[row16+(l&15)][k0+(l>>4)*8 + 0..7]
//   B-frag: lane holds B[k0+(l>>4)*8 + 0..7][col16+(l&15)]  == BT[col][k] contiguous
//   C/D:    col = lane&15, row = (lane>>4)*4 + reg   [measured m89/m91]

__global__ __launch_bounds__(256) void logits_topk_mfma(const ushort* __restrict__ Abf,
                                                        const ushort* __restrict__ BT,
                                                        float* __restrict__ topv,
                                                        ushort* __restrict__ topi){
  __shared__ __align__(16) ushort As[128*32];
  __shared__ __align__(16) ushort Bs[128*32];
  __shared__ float mv[128*2*4];
  __shared__ int   mi[128*2*4];
  int tid=threadIdx.x;
  int w = tid>>6, l = tid&63;
  int wr = w>>1, wc = w&1;
  int g = l>>4, li = l&15;
  int m0 = blockIdx.y*128, n0 = blockIdx.x*128;
  f32x4 acc[4][4] = {};
  for (int kt=0; kt<Dn; kt+=32){
    #pragma unroll
    for (int h=0;h<2;h++){
      int idx = tid + h*256;            // 0..511, 8 bf16 each
      int r = idx>>2, c = (idx&3)*8;
      *(uint4*)&As[r*32+c] = *(const uint4*)&Abf[(size_t)(m0+r)*Dn + kt + c];
      *(uint4*)&Bs[r*32+c] = *(const uint4*)&BT [(size_t)(n0+r)*Dn + kt + c];
    }
    __syncthreads();
    short8 a[4], b[4];
    #pragma unroll
    for (int i=0;i<4;i++) a[i] = *(const short8*)&As[(wr*64 + i*16 + li)*32 + g*8];
    #pragma unroll
    for (int n=0;n<4;n++) b[n] = *(const short8*)&Bs[(wc*64 + n*16 + li)*32 + g*8];
    #pragma unroll
    for (int i=0;i<4;i++)
      #pragma unroll
      for (int n=0;n<4;n++)
        acc[i][n] = __builtin_amdgcn_mfma_f32_16x16x32_bf16(a[i], b[n], acc[i][n], 0, 0, 0);
    __syncthreads();
  }
  // per-wave top-4 over its 64-col range, per row; static indexing only
  #pragma unroll
  for (int i=0;i<4;i++){
    #pragma unroll
    for (int reg=0; reg<4; reg++){
      int rowl = wr*64 + i*16 + g*4 + reg;   // local row 0..127
      float a0=-INFINITY,a1=-INFINITY,a2=-INFINITY,a3=-INFINITY;
      int   x0=0x7fffffff,x1=0x7fffffff,x2=0x7fffffff,x3=0x7fffffff;
      int cb = n0 + wc*64 + li;
      ins4(acc[i][0][reg], cb+ 0, a0,x0,a1,x1,a2,x2,a3,x3);
      ins4(acc[i][1][reg], cb+16, a0,x0,a1,x1,a2,x2,a3,x3);
      ins4(acc[i][2][reg], cb+32, a0,x0,a1,x1,a2,x2,a3,x3);
      ins4(acc[i][3][reg], cb+48, a0,x0,a1,x1,a2,x2,a3,x3);
      #pragma unroll
      for (int mask=1; mask<16; mask<<=1){
        float b0=__shfl_xor(a0,mask,64), b1=__shfl_xor(a1,mask,64);
        float b2=__shfl_xor(a2,mask,64), b3=__shfl_xor(a3,mask,64);
        int   y0=__shfl_xor(x0,mask,64), y1=__shfl_xor(x1,mask,64);
        int   y2=__shfl_xor(x2,mask,64), y3=__shfl_xor(x3,mask,64);
        merge4(a0,x0,a1,x1,a2,x2,a3,x3, b0,y0,b1,y1,b2,y2,b3,y3);
      }
      if (li==0){
        int base = rowl*8 + wc*4;
        mv[base+0]=a0; mv[base+1]=a1; mv[base+2]=a2; mv[base+3]=a3;
        mi[base+0]=x0; mi[base+1]=x1; mi[base+2]=x2; mi[base+3]=x3;
      }
    }
  }
  __syncthreads();
  if (tid < 128){
    int base = tid*8;
    float a0=mv[base+0],a1=mv[base+1],a2=mv[base+2],a3=mv[base+3];
    int   x0=mi[base+0],x1=mi[base+1],x2=mi[base+2],x3=mi[base+3];
    merge4(a0,x0,a1,x1,a2,x2,a3,x3,
           mv[base+4],mi[base+4],mv[base+5],mi[base+5],
           mv[base+6],mi[base+6],mv[base+7],mi[base+7]);
    size_t ob = ((size_t)(m0+tid)*128 + blockIdx.x)*4;
    topv[ob+0]=a0; topv[ob+1]=a1; topv[ob+2]=a2; topv[ob+3]=a3;
    topi[ob+0]=(ushort)x0; topi[ob+1]=(ushort)x1; topi[ob+2]=(ushort)x2; topi[ob+3]=(ushort)x3;
  }
}

// ---------------- 7. merge 128 tile-partials -> global top4 (sorted desc) ----------------

__global__ __launch_bounds__(256) void merge_topk_kernel(const float* __restrict__ topv,
                                                         const ushort* __restrict__ topi,
                                                         int* __restrict__ cand){
  int tid=threadIdx.x, wid=tid>>6, lane=tid&63;
  int row = blockIdx.x*4 + wid;
  size_t base = (size_t)row*512 + (size_t)lane*8;
  float a0=topv[base+0],a1=topv[base+1],a2=topv[base+2],a3=topv[base+3];
  int   x0=topi[base+0],x1=topi[base+1],x2=topi[base+2],x3=topi[base+3];
  float b0=topv[base+4],b1=topv[base+5],b2=topv[base+6],b3=topv[base+7];
  int   y0=topi[base+4],y1=topi[base+5],y2=topi[base+6],y3=topi[base+7];
  merge4(a0,x0,a1,x1,a2,x2,a3,x3, b0,y0,b1,y1,b2,y2,b3,y3);
  #pragma unroll
  for (int mask=1; mask<64; mask<<=1){
    float c0=__shfl_xor(a0,mask,64), c1=__shfl_xor(a1,mask,64);
    float c2=__shfl_xor(a2,mask,64), c3=__shfl_xor(a3,mask,64);
    int   z0=__shfl_xor(x0,mask,64), z1=__shfl_xor(x1,mask,64);
    int   z2=__shfl_xor(x2,mask,64), z3=__shfl_xor(x3,mask,64);
    merge4(a0,x0,a1,x1,a2,x2,a3,x3, c0,z0,c1,z1,c2,z2,c3,z3);
  }
  if (lane==0){
    cand[(size_t)row*4+0]=x0; cand[(size_t)row*4+1]=x1;
    cand[(size_t)row*4+2]=x2; cand[(size_t)row*4+3]=x3;
  }
}

// ------- 8. gather cand_mem, sim, gumbel select, losses, write sel_mem -> cat[:,512:] -------

__global__ __launch_bounds__(256) void select_kernel(const float* __restrict__ cat,
                                                     const int* __restrict__ cand,
                                                     const int* __restrict__ mem_bank,
                                                     const float* __restrict__ tok_emb,
                                                     const float* __restrict__ gu,
                                                     float* __restrict__ cat_out,
                                                     float* __restrict__ losses){
  __shared__ float cm[4][512];
  __shared__ int ids[32];
  __shared__ float wred[15][4];
  __shared__ int sel_s;
  int row=blockIdx.x, tid=threadIdx.x;
  if (tid<32) ids[tid] = mem_bank[(size_t)cand[(size_t)row*4 + (tid>>3)]*KLn + (tid&7)];
  __syncthreads();
  #pragma unroll
  for (int n=0;n<4;n++){
    float s0=0.f, s1=0.f;
    #pragma unroll
    for (int l=0;l<8;l++){
      const float* e = tok_emb + (size_t)ids[n*8+l]*Dn;
      s0 += e[tid]; s1 += e[tid+256];
    }
    cm[n][tid]=s0*0.125f; cm[n][tid+256]=s1*0.125f;
  }
  __syncthreads();
  float hm0 = cat[(size_t)row*1024 + tid], hm1 = cat[(size_t)row*1024 + 256 + tid];
  float c0[4], c1[4];
  #pragma unroll
  for (int n=0;n<4;n++){ c0[n]=cm[n][tid]; c1[n]=cm[n][tid+256]; }
  float p[15];
  p[0]=hm0*hm0+hm1*hm1;
  #pragma unroll
  for (int n=0;n<4;n++) p[1+n]=hm0*c0[n]+hm1*c1[n];
  int qi=5;
  #pragma unroll
  for (int n=0;n<4;n++)
    #pragma unroll
    for (int m=n;m<4;m++) p[qi++]=c0[n]*c0[m]+c1[n]*c1[m];
  int wid=tid>>6, lane=tid&63;
  #pragma unroll
  for (int i=0;i<15;i++) p[i]=wred_sum(p[i]);
  if (lane==0){
    #pragma unroll
    for (int i=0;i<15;i++) wred[i][wid]=p[i];
  }
  __syncthreads();
  if (tid==0){
    float tot[15];
    #pragma unroll
    for (int i=0;i<15;i++) tot[i]=wred[i][0]+wred[i][1]+wred[i][2]+wred[i][3];
    float hn2 = fmaxf(sqrtf(tot[0]), 1e-8f);
    const int diag[4]={5,9,12,14};
    float sim[4], dn[4];
    #pragma unroll
    for (int n=0;n<4;n++){
      float cn = sqrtf(tot[diag[n]]);
      sim[n] = tot[1+n]/(hn2*fmaxf(cn,1e-8f));
      dn[n]  = fmaxf(cn,1e-12f);
    }
    float best=-1e30f; int sel=0;
    #pragma unroll
    for (int n=0;n<4;n++){
      float u = gu[(size_t)row*4+n];
      float g = -logf(-logf(u + 1e-20f) + 1e-20f);
      float a = sim[n]+g;
      if (a>best){ best=a; sel=n; }
    }
    atomicAdd(&losses[0], sim[sel]);
    const int cross[6]={6,7,8,10,11,13};
    const int cn_[6]={0,0,0,1,1,2}, cm_[6]={1,2,3,2,3,3};
    float dv=0.f;
    #pragma unroll
    for (int t=0;t<6;t++) dv += 2.f*tot[cross[t]]/(dn[cn_[t]]*dn[cm_[t]]);
    atomicAdd(&losses[1], dv);
    sel_s=sel;
  }
  __syncthreads();
  int sel=sel_s;
  cat_out[(size_t)row*1024 + 512 + tid]       = cm[sel][tid];
  cat_out[(size_t)row*1024 + 512 + 256 + tid] = cm[sel][tid+256];
}

// ---------------- 12. out = h + sigmoid(g+bg)*(m+bm); losses tail ----------------

__global__ __launch_bounds__(256) void final_kernel(const float* __restrict__ h,
                                                    const float* __restrict__ g,
                                                    const float* __restrict__ m,
                                                    const float* __restrict__ bg,
                                                    const float* __restrict__ bm,
                                                    const float* __restrict__ losses,
                                                    float* __restrict__ out){
  int idx = blockIdx.x*256 + threadIdx.x;
  int n = idx & (Dn-1);
  float gl = g[idx] + bg[n];
  float ml = m[idx] + bm[n];
  float gate = 1.f/(1.f+__expf(-gl));
  out[idx] = h[idx] + gate*ml;
  if (idx==0){
    out[(size_t)Mn*Dn]     = -losses[0]*(1.f/(float)Mn);
    out[(size_t)Mn*Dn + 1] =  losses[1]*(1.f/(float)(Mn*NCn*(NCn-1)));
  }
}

// ---------------- launch ----------------

extern "C" void kernel_launch(void* const* d_in, const int* in_sizes, int n_in,
                              void* d_out, int out_size, void* d_ws, size_t ws_size,
                              hipStream_t stream){
  const float* x           = (const float*)d_in[0];
  const float* pos_cos     = (const float*)d_in[1];
  const float* pos_sin     = (const float*)d_in[2];
  const int*   memory_bank = (const int*)  d_in[3];
  const float* tok_emb     = (const float*)d_in[4];
  const float* wq          = (const float*)d_in[5];
  const float* wk          = (const float*)d_in[6];
  const float* wv          = (const float*)d_in[7];
  const float* wo          = (const float*)d_in[8];
  const float* attn_norm_w = (const float*)d_in[9];
  const float* mem_norm_w  = (const float*)d_in[10];
  const float* w_gate      = (const float*)d_in[11];
  const float* wg_fuse     = (const float*)d_in[12];
  const float* bg_fuse     = (const float*)d_in[13];
  const float* wm_fuse     = (const float*)d_in[14];
  const float* bm_fuse     = (const float*)d_in[15];
  const float* gumbel_u    = (const float*)d_in[16];
  float* out = (float*)d_out;

  char* ws = (char*)d_ws;
  const size_t U = (size_t)Mn*Dn*sizeof(float);   // 8 MB per unit
  // unit 0: hn / attn_pv / abf(4MB)      unit 1: qb / BT[0:8MB] / gbuf
  // unit 2: kb / BT[8:16MB] / mbuf       unit 3: vb / topv(8.39MB, spills into 4)
  // unit 4: h_attn / topi16 @ +1MB       unit 5: hbuf
  // units 6-7: cat (4096x1024)           8U: cand(64KB), losses
  float* hn      = (float*)(ws);
  float* qb      = (float*)(ws + 1*U);
  float* kb      = (float*)(ws + 2*U);
  float* vb      = (float*)(ws + 3*U);
  float* h_attn  = (float*)(ws + 4*U);
  float* hbuf    = (float*)(ws + 5*U);
  float* cat     = (float*)(ws + 6*U);
  int*   cand    = (int*)  (ws + 8*U);
  float* losses  = (float*)(ws + 8*U + 65536);
  float* attn_pv = hn;
  ushort* abf    = (ushort*)(ws);                   // 4096x512 bf16 = 4MB (unit 0)
  ushort* BT     = (ushort*)(ws + 1*U);             // 16384x512 bf16 = 16MB (units 1-2)
  float* topv    = (float*)(ws + 3*U);              // 4096*128*4 f32 = 8.39MB (unit 3 +)
  ushort* topi16 = (ushort*)(ws + 4*U + (1<<20));   // 4096*128*4 u16 = 4.19MB (unit 4)
  float* gbuf    = qb;
  float* mbuf    = kb;

  hipMemsetAsync(losses, 0, 2*sizeof(float), stream);

  rmsnorm_kernel<<<Mn, 256, 0, stream>>>(x, attn_norm_w, hn);

  dim3 g64(Dn/64, Mn/64);   // (8, 64)
  gemm_qkv_kernel<<<g64, 256, 0, stream>>>(hn, wq, pos_cos, pos_sin, qb, 1);
  gemm_qkv_kernel<<<g64, 256, 0, stream>>>(hn, wk, pos_cos, pos_sin, kb, 1);
  gemm_qkv_kernel<<<g64, 256, 0, stream>>>(hn, wv, pos_cos, pos_sin, vb, 0);

  attn_kernel<<<dim3(Sn/64, Bn*NHn), 256, 0, stream>>>(qb, kb, vb, attn_pv);

  gemm_f32_kernel<<<g64, 256, 0, stream>>>(attn_pv, wo, h_attn, 512, 512);

  convert_wgate_kernel<<<dim3(KNn/64, Dn/64), 256, 0, stream>>>(w_gate, BT);

  h_hm_kernel<<<Mn, 256, 0, stream>>>(x, h_attn, mem_norm_w, hbuf, cat, abf);

  logits_topk_mfma<<<dim3(KNn/128, Mn/128), 256, 0, stream>>>(abf, BT, topv, topi16);
  merge_topk_kernel<<<Mn/4, 256, 0, stream>>>(topv, topi16, cand);

  select_kernel<<<Mn, 256, 0, stream>>>(cat, cand, memory_bank, tok_emb, gumbel_u, cat, losses);

  gemm_f32_kernel<<<g64, 256, 0, stream>>>(cat, wg_fuse, gbuf, 1024, 512);
  gemm_f32_kernel<<<g64, 256, 0, stream>>>(cat, wm_fuse, mbuf, 1024, 512);

  final_kernel<<<(Mn*Dn)/256, 256, 0, stream>>>(hbuf, gbuf, mbuf, bg_fuse, bm_fuse, losses, out);
}

// Round 5
// 712.512 us; speedup vs baseline: 55.0093x; 1.5413x over previous
//
#include <hip/hip_runtime.h>
#include <hip/hip_bf16.h>
#include <math.h>

#define Bn 4
#define Sn 1024
#define Dn 512
#define NHn 8
#define HDn 64
#define KNn 16384
#define KLn 8
#define NCn 4
#define Mn (Bn*Sn)   // 4096 rows

typedef __attribute__((ext_vector_type(8))) short short8;
typedef __attribute__((ext_vector_type(4))) float f32x4;
typedef unsigned long long u64;

// ---------------- helpers ----------------

__device__ __forceinline__ float wred_sum(float v){
  #pragma unroll
  for (int m=1;m<64;m<<=1) v += __shfl_xor(v, m, 64);
  return v;
}

__device__ __forceinline__ ushort f2bf(float f){
  __hip_bfloat16 h = __float2bfloat16(f);
  return __builtin_bit_cast(ushort, h);
}

// sortable key: value asc <-> key asc; tie -> smaller index = larger key.
// key = fkey(v)<<32 | (0xFFFF - col). Top-4 = 4 largest keys.
__device__ __forceinline__ unsigned int fkey(float v){
  unsigned int b = __builtin_bit_cast(unsigned int, v);
  return (b & 0x80000000u) ? ~b : (b | 0x80000000u);
}
__device__ __forceinline__ u64 mkkey(float v, int col){
  return ((u64)fkey(v) << 32) | (u64)(0xFFFFu - (unsigned)col);
}

__device__ __forceinline__ void cex64(u64& a, u64& b){
  u64 mx = a > b ? a : b;
  u64 mn = a > b ? b : a;
  a = mx; b = mn;
}
__device__ __forceinline__ void ins4_64(u64 k, u64&k0,u64&k1,u64&k2,u64&k3){
  if (k > k3){
    k3 = k;
    cex64(k2,k3); cex64(k1,k2); cex64(k0,k1);
  }
}
// merge two sorted-desc 4-lists, result (top-4, sorted desc) in a
__device__ __forceinline__ void merge4_64(u64&a0,u64&a1,u64&a2,u64&a3,
                                          u64 b0,u64 b1,u64 b2,u64 b3){
  cex64(a0,b3); cex64(a1,b2); cex64(a2,b1); cex64(a3,b0);
  cex64(a0,a2); cex64(a1,a3);
  cex64(a0,a1); cex64(a2,a3);
}

// ---------------- 1. RMSNorm(x) -> hn (bf16) ----------------

__global__ __launch_bounds__(256) void rmsnorm_kernel(const float* __restrict__ x,
                                                      const float* __restrict__ w,
                                                      ushort* __restrict__ y){
  int row = blockIdx.x, tid = threadIdx.x;
  const float2* xr = (const float2*)(x + (size_t)row*Dn);
  float2 v = xr[tid];
  float ss = v.x*v.x + v.y*v.y;
  ss = wred_sum(ss);
  __shared__ float red[4];
  int wid = tid>>6, lane = tid&63;
  if (lane==0) red[wid]=ss;
  __syncthreads();
  float tot = red[0]+red[1]+red[2]+red[3];
  float sc = rsqrtf(tot*(1.0f/Dn) + 1e-5f);
  float2 wv = ((const float2*)w)[tid];
  ushort2 u; u.x = f2bf(v.x*sc*wv.x); u.y = f2bf(v.y*sc*wv.y);
  *(ushort2*)&y[(size_t)row*Dn + tid*2] = u;
}

// ------- generic transpose-convert: src f32 (K x N) -> dst bf16 (N x K) -------

__global__ __launch_bounds__(256) void convT_kernel(const float* __restrict__ src,
                                                    ushort* __restrict__ dst,
                                                    int ldsrc, int lddst){
  __shared__ float T[64][68];
  int tid=threadIdx.x;
  int n0 = blockIdx.x*64, k0 = blockIdx.y*64;
  #pragma unroll
  for (int h=0;h<4;h++){
    int idx = tid + h*256;
    int r = idx>>4, c = (idx&15)*4;
    float4 v = *(const float4*)&src[(size_t)(k0+r)*ldsrc + n0+c];
    *(float4*)&T[r][c] = v;
  }
  __syncthreads();
  #pragma unroll
  for (int h=0;h<4;h++){
    int idx = tid + h*256;
    int n = idx>>4, kc = (idx&15)*4;
    ushort4 u;
    u.x = f2bf(T[kc+0][n]);
    u.y = f2bf(T[kc+1][n]);
    u.z = f2bf(T[kc+2][n]);
    u.w = f2bf(T[kc+3][n]);
    *(ushort4*)&dst[(size_t)(n0+n)*lddst + k0+kc] = u;
  }
}

// ---------------- generic bf16 MFMA GEMM, 64x64 tile, BK=64 ----------------
// A bf16 (M x K) row-major lda; BT bf16 (N x K) row-major (= B^T), ldb = K.
// MODE 0: C[mm*ldc+n] = val (f32)
// MODE 1: relayout (B,NH,S,HD) + RoPE
// MODE 2: relayout only

template<int MODE>
__global__ __launch_bounds__(256) void gemm_bf16(const ushort* __restrict__ A, int lda,
                                                 const ushort* __restrict__ BT, int K,
                                                 float* __restrict__ C, int ldc,
                                                 const float* __restrict__ pc,
                                                 const float* __restrict__ ps){
  __shared__ __align__(16) ushort As[64*72];
  __shared__ __align__(16) ushort Bs[64*72];
  int tid=threadIdx.x;
  int w = tid>>6, l = tid&63;
  int wr = w>>1, wc = w&1;
  int g = l>>4, li = l&15;
  int m0 = blockIdx.y*64, n0 = blockIdx.x*64;
  f32x4 acc[2][2] = {};
  for (int kt=0; kt<K; kt+=64){
    #pragma unroll
    for (int t=0;t<2;t++){
      int ch = tid + t*256;          // 0..511
      int r = ch>>3, c = (ch&7)*8;
      *(uint4*)&As[r*72+c] = *(const uint4*)&A [(size_t)(m0+r)*lda + kt + c];
      *(uint4*)&Bs[r*72+c] = *(const uint4*)&BT[(size_t)(n0+r)*K   + kt + c];
    }
    __syncthreads();
    #pragma unroll
    for (int kk=0;kk<2;kk++){
      short8 a0 = *(const short8*)&As[(wr*32 +      li)*72 + kk*32 + g*8];
      short8 a1 = *(const short8*)&As[(wr*32 + 16 + li)*72 + kk*32 + g*8];
      short8 b0 = *(const short8*)&Bs[(wc*32 +      li)*72 + kk*32 + g*8];
      short8 b1 = *(const short8*)&Bs[(wc*32 + 16 + li)*72 + kk*32 + g*8];
      acc[0][0] = __builtin_amdgcn_mfma_f32_16x16x32_bf16(a0, b0, acc[0][0], 0,0,0);
      acc[0][1] = __builtin_amdgcn_mfma_f32_16x16x32_bf16(a0, b1, acc[0][1], 0,0,0);
      acc[1][0] = __builtin_amdgcn_mfma_f32_16x16x32_bf16(a1, b0, acc[1][0], 0,0,0);
      acc[1][1] = __builtin_amdgcn_mfma_f32_16x16x32_bf16(a1, b1, acc[1][1], 0,0,0);
    }
    __syncthreads();
  }
  #pragma unroll
  for (int mi=0;mi<2;mi++){
    #pragma unroll
    for (int ni=0;ni<2;ni++){
      #pragma unroll
      for (int reg=0;reg<4;reg++){
        int mm = m0 + wr*32 + mi*16 + g*4 + reg;
        int n  = n0 + wc*32 + ni*16 + li;
        float val = acc[mi][ni][reg];
        if (MODE==0){
          C[(size_t)mm*ldc + n] = val;
        } else {
          int b = mm>>10, s2 = mm&1023, h = n>>6, d = n&63;
          size_t o = ((size_t)(b*NHn + h)*Sn + s2)*HDn + d;
          if (MODE==2){
            C[o] = val;
          } else {
            float other = __shfl_xor(val, 1, 64);
            float cc = pc[s2*32 + (d>>1)], snv = ps[s2*32 + (d>>1)];
            C[o] = ((li&1)==0) ? val*cc - other*snv : other*snv + val*cc;
          }
        }
      }
    }
  }
}

// ---------------- 3. causal flash attention, f32, 64x64 tiles; bf16 out ----------------

__global__ __launch_bounds__(256) void attn_kernel(const float* __restrict__ q,
                                                   const float* __restrict__ k,
                                                   const float* __restrict__ v,
                                                   ushort* __restrict__ o){
  __shared__ float Qs[64][65];
  __shared__ float KPs[64][65];
  __shared__ float Vs[64][65];
  __shared__ float mArr[64], lArr[64], aArr[64];
  int tid=threadIdx.x, tx=tid&15, ty=tid>>4;
  int qt=blockIdx.x, bh=blockIdx.y;
  const float* Qp = q + (size_t)bh*Sn*HDn + (size_t)qt*64*HDn;
  const float* Kp = k + (size_t)bh*Sn*HDn;
  const float* Vp = v + (size_t)bh*Sn*HDn;
  #pragma unroll
  for (int t=0;t<16;t++){ int i=tid+t*256; int r=i>>6, c=i&63; Qs[r][c]=Qp[(size_t)r*64+c]; }
  if (tid<64){ mArr[tid]=-1e30f; lArr[tid]=0.f; }
  float O[4][4] = {};
  __syncthreads();
  for (int kt=0; kt<=qt; kt++){
    #pragma unroll
    for (int t=0;t<16;t++){
      int i=tid+t*256; int r=i>>6, c=i&63;
      KPs[r][c]=Kp[(size_t)(kt*64+r)*64+c];
      Vs[r][c] =Vp[(size_t)(kt*64+r)*64+c];
    }
    __syncthreads();
    float sc[4][4] = {};
    #pragma unroll 8
    for (int d=0; d<64; d++){
      float a[4], b[4];
      #pragma unroll
      for (int i=0;i<4;i++) a[i]=Qs[ty*4+i][d];
      #pragma unroll
      for (int j=0;j<4;j++) b[j]=KPs[tx*4+j][d];
      #pragma unroll
      for (int i=0;i<4;i++)
        #pragma unroll
        for (int j=0;j<4;j++) sc[i][j] += a[i]*b[j];
    }
    __syncthreads();
    #pragma unroll
    for (int i=0;i<4;i++){
      int qg = qt*64+ty*4+i;
      #pragma unroll
      for (int j=0;j<4;j++){
        int kg = kt*64+tx*4+j;
        KPs[ty*4+i][tx*4+j] = (kg<=qg) ? sc[i][j]*0.125f : -1e9f;
      }
    }
    __syncthreads();
    {
      int r = tid>>2, sub = tid&3;
      float mt = -1e30f;
      #pragma unroll
      for (int c=0;c<16;c++) mt = fmaxf(mt, KPs[r][sub*16+c]);
      mt = fmaxf(mt, __shfl_xor(mt,1,64));
      mt = fmaxf(mt, __shfl_xor(mt,2,64));
      float mn = fmaxf(mArr[r], mt);
      float sum = 0.f;
      #pragma unroll
      for (int c=0;c<16;c++){
        float p = __expf(KPs[r][sub*16+c]-mn);
        KPs[r][sub*16+c] = p;
        sum += p;
      }
      sum += __shfl_xor(sum,1,64);
      sum += __shfl_xor(sum,2,64);
      if (sub==0){
        float al = __expf(mArr[r]-mn);
        lArr[r] = lArr[r]*al + sum;
        aArr[r] = al;
        mArr[r] = mn;
      }
    }
    __syncthreads();
    #pragma unroll
    for (int i=0;i<4;i++){ float al=aArr[ty*4+i];
      #pragma unroll
      for (int j=0;j<4;j++) O[i][j]*=al; }
    #pragma unroll 8
    for (int kk=0; kk<64; kk++){
      float p[4], vv[4];
      #pragma unroll
      for (int i=0;i<4;i++) p[i]=KPs[ty*4+i][kk];
      #pragma unroll
      for (int j=0;j<4;j++) vv[j]=Vs[kk][tx*4+j];
      #pragma unroll
      for (int i=0;i<4;i++)
        #pragma unroll
        for (int j=0;j<4;j++) O[i][j] += p[i]*vv[j];
    }
    __syncthreads();
  }
  int b=bh>>3, h=bh&7;
  #pragma unroll
  for (int i=0;i<4;i++){
    int qg = qt*64+ty*4+i;
    float inv = 1.f/lArr[ty*4+i];
    #pragma unroll
    for (int j=0;j<4;j++)
      o[((size_t)(b*Sn+qg))*Dn + h*HDn + tx*4+j] = f2bf(O[i][j]*inv);
  }
}

// --- 5. h = x + h_attn ; hm = rms(h_attn)*w -> hm32 (f32) + cat_bf[:, :512] (bf16) ---

__global__ __launch_bounds__(256) void h_hm_kernel(const float* __restrict__ x,
                                                   const float* __restrict__ ha,
                                                   const float* __restrict__ w,
                                                   float* __restrict__ h,
                                                   float* __restrict__ hm32,
                                                   ushort* __restrict__ cat_bf){
  int row=blockIdx.x, tid=threadIdx.x;
  float2 a = ((const float2*)(ha + (size_t)row*Dn))[tid];
  float2 xv = ((const float2*)(x + (size_t)row*Dn))[tid];
  float ss = a.x*a.x + a.y*a.y;
  ss = wred_sum(ss);
  __shared__ float red[4];
  int wid=tid>>6, lane=tid&63;
  if (lane==0) red[wid]=ss;
  __syncthreads();
  float tot = red[0]+red[1]+red[2]+red[3];
  float sc = rsqrtf(tot*(1.0f/Dn) + 1e-5f);
  float2 wv = ((const float2*)w)[tid];
  float hm0 = a.x*sc*wv.x, hm1 = a.y*sc*wv.y;
  ((float2*)(h + (size_t)row*Dn))[tid] = make_float2(xv.x+a.x, xv.y+a.y);
  ((float2*)(hm32 + (size_t)row*Dn))[tid] = make_float2(hm0, hm1);
  ushort2 u; u.x = f2bf(hm0); u.y = f2bf(hm1);
  *(ushort2*)&cat_bf[(size_t)row*1024 + tid*2] = u;
}

// ---------------- 6. bf16 MFMA logits GEMM + fused top-4 (u64 keys) ----------------
// A = cat_bf (4096x1024, hm in cols 0..511), BTg (16384x512 bf16).
// 128x128 tile, BK=32, 4 waves 2x2. LDS rows padded to 40 ushorts (bank-period 8).
// Epilogue: acc -> LDS transpose (4 slices of 32x132 f32, aliases staging) ->
// 8 threads/row scan + 3-round u64 butterfly -> one sorted top-4 per (row, block).

__global__ __launch_bounds__(256) void logits_topk_mfma(const ushort* __restrict__ Abf,
                                                        const ushort* __restrict__ BT,
                                                        u64* __restrict__ keys){
  __shared__ __align__(16) char smem[2*128*40*2];      // 20480 B
  ushort* As = (ushort*)smem;                          // [128][40]
  ushort* Bs = (ushort*)(smem + 128*40*2);             // [128][40]
  float*  Ls = (float*)smem;                           // [32][132] = 16896 B (epilogue alias)
  int tid=threadIdx.x;
  int w = tid>>6, l = tid&63;
  int wr = w>>1, wc = w&1;
  int g = l>>4, li = l&15;
  int m0 = blockIdx.y*128, n0 = blockIdx.x*128;
  f32x4 acc[4][4] = {};
  for (int kt=0; kt<Dn; kt+=32){
    #pragma unroll
    for (int t=0;t<2;t++){
      int ch = tid + t*256;            // 0..511
      int r = ch>>2, c = (ch&3)*8;
      *(uint4*)&As[r*40+c] = *(const uint4*)&Abf[(size_t)(m0+r)*1024 + kt + c];
      *(uint4*)&Bs[r*40+c] = *(const uint4*)&BT [(size_t)(n0+r)*Dn   + kt + c];
    }
    __syncthreads();
    short8 a[4], b[4];
    #pragma unroll
    for (int i=0;i<4;i++) a[i] = *(const short8*)&As[(wr*64 + i*16 + li)*40 + g*8];
    #pragma unroll
    for (int n=0;n<4;n++) b[n] = *(const short8*)&Bs[(wc*64 + n*16 + li)*40 + g*8];
    #pragma unroll
    for (int i=0;i<4;i++)
      #pragma unroll
      for (int n=0;n<4;n++)
        acc[i][n] = __builtin_amdgcn_mfma_f32_16x16x32_bf16(a[i], b[n], acc[i][n], 0, 0, 0);
    __syncthreads();
  }
  // epilogue: 4 slices, each 32 rows x 128 cols
  for (int i=0;i<4;i++){
    // phase A: scatter acc slice to Ls
    #pragma unroll
    for (int n=0;n<4;n++)
      #pragma unroll
      for (int reg=0;reg<4;reg++)
        Ls[(wr*16 + g*4 + reg)*132 + wc*64 + n*16 + li] = acc[i][n][reg];
    __syncthreads();
    // phase B: 8 threads per row scan 16 cols each
    {
      int r = tid>>3, s = tid&7;
      u64 k0=0,k1=0,k2=0,k3=0;
      #pragma unroll
      for (int c4=0;c4<4;c4++){
        float4 vv = *(const float4*)&Ls[r*132 + s*16 + c4*4];
        int cb = n0 + s*16 + c4*4;
        ins4_64(mkkey(vv.x, cb+0), k0,k1,k2,k3);
        ins4_64(mkkey(vv.y, cb+1), k0,k1,k2,k3);
        ins4_64(mkkey(vv.z, cb+2), k0,k1,k2,k3);
        ins4_64(mkkey(vv.w, cb+3), k0,k1,k2,k3);
      }
      #pragma unroll
      for (int mask=1; mask<8; mask<<=1){
        u64 b0=__shfl_xor(k0,mask,64), b1=__shfl_xor(k1,mask,64);
        u64 b2=__shfl_xor(k2,mask,64), b3=__shfl_xor(k3,mask,64);
        merge4_64(k0,k1,k2,k3, b0,b1,b2,b3);
      }
      if (s==0){
        size_t grow = m0 + ((r>>4)*64 + i*16 + (r&15));
        size_t ob = (grow*128 + blockIdx.x)*4;
        keys[ob+0]=k0; keys[ob+1]=k1; keys[ob+2]=k2; keys[ob+3]=k3;
      }
    }
    __syncthreads();
  }
}

// ---------------- 7. merge 128 tile-partials -> global top4 (sorted desc) ----------------

__global__ __launch_bounds__(256) void merge_topk_kernel(const u64* __restrict__ keys,
                                                         int* __restrict__ cand){
  int tid=threadIdx.x, wid=tid>>6, lane=tid&63;
  int row = blockIdx.x*4 + wid;
  size_t base = (size_t)row*512 + (size_t)lane*8;
  u64 k0=keys[base+0],k1=keys[base+1],k2=keys[base+2],k3=keys[base+3];
  merge4_64(k0,k1,k2,k3, keys[base+4],keys[base+5],keys[base+6],keys[base+7]);
  #pragma unroll
  for (int mask=1; mask<64; mask<<=1){
    u64 b0=__shfl_xor(k0,mask,64), b1=__shfl_xor(k1,mask,64);
    u64 b2=__shfl_xor(k2,mask,64), b3=__shfl_xor(k3,mask,64);
    merge4_64(k0,k1,k2,k3, b0,b1,b2,b3);
  }
  if (lane==0){
    cand[(size_t)row*4+0]=(int)(0xFFFFu - (unsigned)(k0 & 0xFFFFu));
    cand[(size_t)row*4+1]=(int)(0xFFFFu - (unsigned)(k1 & 0xFFFFu));
    cand[(size_t)row*4+2]=(int)(0xFFFFu - (unsigned)(k2 & 0xFFFFu));
    cand[(size_t)row*4+3]=(int)(0xFFFFu - (unsigned)(k3 & 0xFFFFu));
  }
}

// ------- 8. gather cand_mem, sim, gumbel select, losses, write sel_mem -> cat_bf[:,512:] -------

__global__ __launch_bounds__(256) void select_kernel(const float* __restrict__ hm32,
                                                     const int* __restrict__ cand,
                                                     const int* __restrict__ mem_bank,
                                                     const float* __restrict__ tok_emb,
                                                     const float* __restrict__ gu,
                                                     ushort* __restrict__ cat_bf,
                                                     float* __restrict__ losses){
  __shared__ float cm[4][512];
  __shared__ int ids[32];
  __shared__ float wred[15][4];
  __shared__ int sel_s;
  int row=blockIdx.x, tid=threadIdx.x;
  if (tid<32) ids[tid] = mem_bank[(size_t)cand[(size_t)row*4 + (tid>>3)]*KLn + (tid&7)];
  __syncthreads();
  #pragma unroll
  for (int n=0;n<4;n++){
    float s0=0.f, s1=0.f;
    #pragma unroll
    for (int l=0;l<8;l++){
      const float* e = tok_emb + (size_t)ids[n*8+l]*Dn;
      s0 += e[tid]; s1 += e[tid+256];
    }
    cm[n][tid]=s0*0.125f; cm[n][tid+256]=s1*0.125f;
  }
  __syncthreads();
  float hm0 = hm32[(size_t)row*Dn + tid], hm1 = hm32[(size_t)row*Dn + 256 + tid];
  float c0[4], c1[4];
  #pragma unroll
  for (int n=0;n<4;n++){ c0[n]=cm[n][tid]; c1[n]=cm[n][tid+256]; }
  float p[15];
  p[0]=hm0*hm0+hm1*hm1;
  #pragma unroll
  for (int n=0;n<4;n++) p[1+n]=hm0*c0[n]+hm1*c1[n];
  int qi=5;
  #pragma unroll
  for (int n=0;n<4;n++)
    #pragma unroll
    for (int m=n;m<4;m++) p[qi++]=c0[n]*c0[m]+c1[n]*c1[m];
  int wid=tid>>6, lane=tid&63;
  #pragma unroll
  for (int i=0;i<15;i++) p[i]=wred_sum(p[i]);
  if (lane==0){
    #pragma unroll
    for (int i=0;i<15;i++) wred[i][wid]=p[i];
  }
  __syncthreads();
  if (tid==0){
    float tot[15];
    #pragma unroll
    for (int i=0;i<15;i++) tot[i]=wred[i][0]+wred[i][1]+wred[i][2]+wred[i][3];
    float hn2 = fmaxf(sqrtf(tot[0]), 1e-8f);
    const int diag[4]={5,9,12,14};
    float sim[4], dn[4];
    #pragma unroll
    for (int n=0;n<4;n++){
      float cn = sqrtf(tot[diag[n]]);
      sim[n] = tot[1+n]/(hn2*fmaxf(cn,1e-8f));
      dn[n]  = fmaxf(cn,1e-12f);
    }
    float best=-1e30f; int sel=0;
    #pragma unroll
    for (int n=0;n<4;n++){
      float u = gu[(size_t)row*4+n];
      float g = -logf(-logf(u + 1e-20f) + 1e-20f);
      float a = sim[n]+g;
      if (a>best){ best=a; sel=n; }
    }
    atomicAdd(&losses[0], sim[sel]);
    const int cross[6]={6,7,8,10,11,13};
    const int cn_[6]={0,0,0,1,1,2}, cm_[6]={1,2,3,2,3,3};
    float dv=0.f;
    #pragma unroll
    for (int t=0;t<6;t++) dv += 2.f*tot[cross[t]]/(dn[cn_[t]]*dn[cm_[t]]);
    atomicAdd(&losses[1], dv);
    sel_s=sel;
  }
  __syncthreads();
  int sel=sel_s;
  cat_bf[(size_t)row*1024 + 512 + tid]       = f2bf(cm[sel][tid]);
  cat_bf[(size_t)row*1024 + 512 + 256 + tid] = f2bf(cm[sel][tid+256]);
}

// ---------------- 12. out = h + sigmoid(g+bg)*(m+bm); losses tail ----------------

__global__ __launch_bounds__(256) void final_kernel(const float* __restrict__ h,
                                                    const float* __restrict__ g,
                                                    const float* __restrict__ m,
                                                    const float* __restrict__ bg,
                                                    const float* __restrict__ bm,
                                                    const float* __restrict__ losses,
                                                    float* __restrict__ out){
  int idx = blockIdx.x*256 + threadIdx.x;
  int n = idx & (Dn-1);
  float gl = g[idx] + bg[n];
  float ml = m[idx] + bm[n];
  float gate = 1.f/(1.f+__expf(-gl));
  out[idx] = h[idx] + gate*ml;
  if (idx==0){
    out[(size_t)Mn*Dn]     = -losses[0]*(1.f/(float)Mn);
    out[(size_t)Mn*Dn + 1] =  losses[1]*(1.f/(float)(Mn*NCn*(NCn-1)));
  }
}

// ---------------- launch ----------------

extern "C" void kernel_launch(void* const* d_in, const int* in_sizes, int n_in,
                              void* d_out, int out_size, void* d_ws, size_t ws_size,
                              hipStream_t stream){
  const float* x           = (const float*)d_in[0];
  const float* pos_cos     = (const float*)d_in[1];
  const float* pos_sin     = (const float*)d_in[2];
  const int*   memory_bank = (const int*)  d_in[3];
  const float* tok_emb     = (const float*)d_in[4];
  const float* wq          = (const float*)d_in[5];
  const float* wk          = (const float*)d_in[6];
  const float* wv          = (const float*)d_in[7];
  const float* wo          = (const float*)d_in[8];
  const float* attn_norm_w = (const float*)d_in[9];
  const float* mem_norm_w  = (const float*)d_in[10];
  const float* w_gate      = (const float*)d_in[11];
  const float* wg_fuse     = (const float*)d_in[12];
  const float* bg_fuse     = (const float*)d_in[13];
  const float* wm_fuse     = (const float*)d_in[14];
  const float* bm_fuse     = (const float*)d_in[15];
  const float* gumbel_u    = (const float*)d_in[16];
  float* out = (float*)d_out;

  char* ws = (char*)d_ws;
  const size_t MB = 1u<<20;
  // 0-16MB: BTg | 16-18: wqT,wkT,wvT,woT | 18-20: wgfT,wmfT
  // 20-24: hn_bf -> pv_bf | 24-32: q -> hbuf | 32-40: k -> hm32 | 40-48: v -> cat_bf
  // 48-56: h_attn -> keys[0:8MB] -> gbuf | 56-64: keys[8:16MB] -> mbuf
  // 64MB: cand (64KB) | 64MB+64KB: losses
  ushort* BTg    = (ushort*)(ws);
  ushort* wqT    = (ushort*)(ws + 16*MB);
  ushort* wkT    = (ushort*)(ws + 16*MB + 512*1024);
  ushort* wvT    = (ushort*)(ws + 17*MB);
  ushort* woT    = (ushort*)(ws + 17*MB + 512*1024);
  ushort* wgfT   = (ushort*)(ws + 18*MB);
  ushort* wmfT   = (ushort*)(ws + 19*MB);
  ushort* hn_bf  = (ushort*)(ws + 20*MB);
  ushort* pv_bf  = (ushort*)(ws + 20*MB);
  float*  qb     = (float*)(ws + 24*MB);
  float*  hbuf   = (float*)(ws + 24*MB);
  float*  kb     = (float*)(ws + 32*MB);
  float*  hm32   = (float*)(ws + 32*MB);
  float*  vb     = (float*)(ws + 40*MB);
  ushort* cat_bf = (ushort*)(ws + 40*MB);
  float*  h_attn = (float*)(ws + 48*MB);
  u64*    keys   = (u64*)  (ws + 48*MB);
  float*  gbuf   = (float*)(ws + 48*MB);
  float*  mbuf   = (float*)(ws + 56*MB);
  int*    cand   = (int*)  (ws + 64*MB);
  float*  losses = (float*)(ws + 64*MB + 65536);

  hipMemsetAsync(losses, 0, 2*sizeof(float), stream);

  // weight transpose-converts (f32 KxN -> bf16 NxK)
  convT_kernel<<<dim3(8,8),     256, 0, stream>>>(wq,      wqT,  512,  512);
  convT_kernel<<<dim3(8,8),     256, 0, stream>>>(wk,      wkT,  512,  512);
  convT_kernel<<<dim3(8,8),     256, 0, stream>>>(wv,      wvT,  512,  512);
  convT_kernel<<<dim3(8,8),     256, 0, stream>>>(wo,      woT,  512,  512);
  convT_kernel<<<dim3(8,16),    256, 0, stream>>>(wg_fuse, wgfT, 512,  1024);
  convT_kernel<<<dim3(8,16),    256, 0, stream>>>(wm_fuse, wmfT, 512,  1024);
  convT_kernel<<<dim3(256,8),   256, 0, stream>>>(w_gate,  BTg,  KNn,  512);

  rmsnorm_kernel<<<Mn, 256, 0, stream>>>(x, attn_norm_w, hn_bf);

  dim3 g64(Dn/64, Mn/64);   // (8, 64)
  gemm_bf16<1><<<g64, 256, 0, stream>>>(hn_bf, 512, wqT, 512, qb, 0, pos_cos, pos_sin);
  gemm_bf16<1><<<g64, 256, 0, stream>>>(hn_bf, 512, wkT, 512, kb, 0, pos_cos, pos_sin);
  gemm_bf16<2><<<g64, 256, 0, stream>>>(hn_bf, 512, wvT, 512, vb, 0, nullptr, nullptr);

  attn_kernel<<<dim3(Sn/64, Bn*NHn), 256, 0, stream>>>(qb, kb, vb, pv_bf);

  gemm_bf16<0><<<g64, 256, 0, stream>>>(pv_bf, 512, woT, 512, h_attn, 512, nullptr, nullptr);

  h_hm_kernel<<<Mn, 256, 0, stream>>>(x, h_attn, mem_norm_w, hbuf, hm32, cat_bf);

  logits_topk_mfma<<<dim3(KNn/128, Mn/128), 256, 0, stream>>>(cat_bf, BTg, keys);
  merge_topk_kernel<<<Mn/4, 256, 0, stream>>>(keys, cand);

  select_kernel<<<Mn, 256, 0, stream>>>(hm32, cand, memory_bank, tok_emb, gumbel_u, cat_bf, losses);

  gemm_bf16<0><<<g64, 256, 0, stream>>>(cat_bf, 1024, wgfT, 1024, gbuf, 512, nullptr, nullptr);
  gemm_bf16<0><<<g64, 256, 0, stream>>>(cat_bf, 1024, wmfT, 1024, mbuf, 512, nullptr, nullptr);

  final_kernel<<<(Mn*Dn)/256, 256, 0, stream>>>(hbuf, gbuf, mbuf, bg_fuse, bm_fuse, losses, out);
}

// Round 7
// 563.676 us; speedup vs baseline: 69.5343x; 1.2640x over previous
//
#include <hip/hip_runtime.h>
#include <hip/hip_bf16.h>
#include <math.h>

#define Bn 4
#define Sn 1024
#define Dn 512
#define NHn 8
#define HDn 64
#define KNn 16384
#define KLn 8
#define NCn 4
#define Mn (Bn*Sn)   // 4096 rows

typedef __attribute__((ext_vector_type(8))) short short8;
typedef __attribute__((ext_vector_type(4))) float f32x4;
typedef unsigned long long u64;

#define MFMA16(a,b,c) __builtin_amdgcn_mfma_f32_16x16x32_bf16(a,b,c,0,0,0)

// ---------------- helpers ----------------

__device__ __forceinline__ float wred_sum(float v){
  #pragma unroll
  for (int m=1;m<64;m<<=1) v += __shfl_xor(v, m, 64);
  return v;
}

__device__ __forceinline__ ushort f2bf(float f){
  __hip_bfloat16 h = __float2bfloat16(f);
  return __builtin_bit_cast(ushort, h);
}
__device__ __forceinline__ float bf2f(ushort u){
  return __builtin_bit_cast(float, ((unsigned)u)<<16);
}

// sortable key: value asc <-> key asc; tie -> smaller index = larger key.
__device__ __forceinline__ unsigned int fkey(float v){
  unsigned int b = __builtin_bit_cast(unsigned int, v);
  return (b & 0x80000000u) ? ~b : (b | 0x80000000u);
}
__device__ __forceinline__ u64 mkkey(float v, int col){
  return ((u64)fkey(v) << 32) | (u64)(0xFFFFu - (unsigned)col);
}

__device__ __forceinline__ void cex64(u64& a, u64& b){
  u64 mx = a > b ? a : b;
  u64 mn = a > b ? b : a;
  a = mx; b = mn;
}
__device__ __forceinline__ void ins4_64(u64 k, u64&k0,u64&k1,u64&k2,u64&k3){
  if (k > k3){
    k3 = k;
    cex64(k2,k3); cex64(k1,k2); cex64(k0,k1);
  }
}
__device__ __forceinline__ void merge4_64(u64&a0,u64&a1,u64&a2,u64&a3,
                                          u64 b0,u64 b1,u64 b2,u64 b3){
  cex64(a0,b3); cex64(a1,b2); cex64(a2,b1); cex64(a3,b0);
  cex64(a0,a2); cex64(a1,a3);
  cex64(a0,a1); cex64(a2,a3);
}

// ---------------- 1. RMSNorm(x) -> hn (bf16) ----------------

__global__ __launch_bounds__(256) void rmsnorm_kernel(const float* __restrict__ x,
                                                      const float* __restrict__ w,
                                                      ushort* __restrict__ y){
  int row = blockIdx.x, tid = threadIdx.x;
  const float2* xr = (const float2*)(x + (size_t)row*Dn);
  float2 v = xr[tid];
  float ss = v.x*v.x + v.y*v.y;
  ss = wred_sum(ss);
  __shared__ float red[4];
  int wid = tid>>6, lane = tid&63;
  if (lane==0) red[wid]=ss;
  __syncthreads();
  float tot = red[0]+red[1]+red[2]+red[3];
  float sc = rsqrtf(tot*(1.0f/Dn) + 1e-5f);
  float2 wv = ((const float2*)w)[tid];
  ushort2 u; u.x = f2bf(v.x*sc*wv.x); u.y = f2bf(v.y*sc*wv.y);
  *(ushort2*)&y[(size_t)row*Dn + tid*2] = u;
}

// ------- generic transpose-convert: src f32 (K x N) -> dst bf16 (N x K) -------

__global__ __launch_bounds__(256) void convT_kernel(const float* __restrict__ src,
                                                    ushort* __restrict__ dst,
                                                    int ldsrc, int lddst){
  __shared__ float T[64][68];
  int tid=threadIdx.x;
  int n0 = blockIdx.x*64, k0 = blockIdx.y*64;
  #pragma unroll
  for (int h=0;h<4;h++){
    int idx = tid + h*256;
    int r = idx>>4, c = (idx&15)*4;
    float4 v = *(const float4*)&src[(size_t)(k0+r)*ldsrc + n0+c];
    *(float4*)&T[r][c] = v;
  }
  __syncthreads();
  #pragma unroll
  for (int h=0;h<4;h++){
    int idx = tid + h*256;
    int n = idx>>4, kc = (idx&15)*4;
    ushort4 u;
    u.x = f2bf(T[kc+0][n]);
    u.y = f2bf(T[kc+1][n]);
    u.z = f2bf(T[kc+2][n]);
    u.w = f2bf(T[kc+3][n]);
    *(ushort4*)&dst[(size_t)(n0+n)*lddst + k0+kc] = u;
  }
}

// ---------------- generic bf16 MFMA GEMM, 64x64 tile, BK=64 ----------------
// MODE 0: f32 C[mm*ldc+n] = val
// MODE 1: bf16 out, relayout (B,NH,S,HD) + RoPE
// MODE 2: bf16 out, relayout only
// MODE 3: bf16 out, plain row-major

template<int MODE>
__global__ __launch_bounds__(256) void gemm_bf16(const ushort* __restrict__ A, int lda,
                                                 const ushort* __restrict__ BT, int K,
                                                 void* __restrict__ Cv, int ldc,
                                                 const float* __restrict__ pc,
                                                 const float* __restrict__ ps){
  __shared__ __align__(16) ushort As[64*72];
  __shared__ __align__(16) ushort Bs[64*72];
  int tid=threadIdx.x;
  int w = tid>>6, l = tid&63;
  int wr = w>>1, wc = w&1;
  int g = l>>4, li = l&15;
  int m0 = blockIdx.y*64, n0 = blockIdx.x*64;
  f32x4 acc[2][2] = {};
  for (int kt=0; kt<K; kt+=64){
    #pragma unroll
    for (int t=0;t<2;t++){
      int ch = tid + t*256;
      int r = ch>>3, c = (ch&7)*8;
      *(uint4*)&As[r*72+c] = *(const uint4*)&A [(size_t)(m0+r)*lda + kt + c];
      *(uint4*)&Bs[r*72+c] = *(const uint4*)&BT[(size_t)(n0+r)*K   + kt + c];
    }
    __syncthreads();
    #pragma unroll
    for (int kk=0;kk<2;kk++){
      short8 a0 = *(const short8*)&As[(wr*32 +      li)*72 + kk*32 + g*8];
      short8 a1 = *(const short8*)&As[(wr*32 + 16 + li)*72 + kk*32 + g*8];
      short8 b0 = *(const short8*)&Bs[(wc*32 +      li)*72 + kk*32 + g*8];
      short8 b1 = *(const short8*)&Bs[(wc*32 + 16 + li)*72 + kk*32 + g*8];
      acc[0][0] = MFMA16(a0, b0, acc[0][0]);
      acc[0][1] = MFMA16(a0, b1, acc[0][1]);
      acc[1][0] = MFMA16(a1, b0, acc[1][0]);
      acc[1][1] = MFMA16(a1, b1, acc[1][1]);
    }
    __syncthreads();
  }
  #pragma unroll
  for (int mi=0;mi<2;mi++){
    #pragma unroll
    for (int ni=0;ni<2;ni++){
      #pragma unroll
      for (int reg=0;reg<4;reg++){
        int mm = m0 + wr*32 + mi*16 + g*4 + reg;
        int n  = n0 + wc*32 + ni*16 + li;
        float val = acc[mi][ni][reg];
        if (MODE==0){
          ((float*)Cv)[(size_t)mm*ldc + n] = val;
        } else if (MODE==3){
          ((ushort*)Cv)[(size_t)mm*ldc + n] = f2bf(val);
        } else {
          int b = mm>>10, s2 = mm&1023, h = n>>6, d = n&63;
          size_t o = ((size_t)(b*NHn + h)*Sn + s2)*HDn + d;
          if (MODE==2){
            ((ushort*)Cv)[o] = f2bf(val);
          } else {
            float other = __shfl_xor(val, 1, 64);
            float cc = pc[s2*32 + (d>>1)], snv = ps[s2*32 + (d>>1)];
            float rv = ((li&1)==0) ? val*cc - other*snv : other*snv + val*cc;
            ((ushort*)Cv)[o] = f2bf(rv);
          }
        }
      }
    }
  }
}

// ---------------- 3. bf16 MFMA causal flash attention ----------------
// Q,K,V bf16 (B*NH, S, 64). Block: 64 q-rows of one head; 4 waves x 16 rows.
// K_lds [64][72]; VT_lds [64 d][64 kv] granule-XOR-swizzled; P per-wave [16][72].

__global__ __launch_bounds__(256) void attn_mfma(const ushort* __restrict__ q,
                                                 const ushort* __restrict__ k,
                                                 const ushort* __restrict__ v,
                                                 ushort* __restrict__ o){
  __shared__ __align__(16) ushort Ks[64*72];
  __shared__ __align__(16) ushort VTs[64*64];
  __shared__ __align__(16) ushort Ps[4][16*72];
  int tid = threadIdx.x;
  int w = tid>>6, l = tid&63;
  int g = l>>4, li = l&15;
  int qt = blockIdx.x, bh = blockIdx.y;
  const ushort* Qg = q + ((size_t)bh*Sn + qt*64 + w*16)*HDn;
  const ushort* Kg = k + (size_t)bh*Sn*HDn;
  const ushort* Vg = v + (size_t)bh*Sn*HDn;
  short8 aq0 = *(const short8*)&Qg[(size_t)li*HDn + g*8];
  short8 aq1 = *(const short8*)&Qg[(size_t)li*HDn + 32 + g*8];
  f32x4 oacc[4] = {};
  float mreg[4] = {-1e30f,-1e30f,-1e30f,-1e30f};
  float lreg[4] = {0.f,0.f,0.f,0.f};
  for (int kt=0; kt<=qt; kt++){
    // ---- stage K and V^T ----
    #pragma unroll
    for (int t=0;t<2;t++){
      int ch = tid + t*256;
      int r = ch>>3, c = (ch&7)*8;
      short8 kv8 = *(const short8*)&Kg[(size_t)(kt*64+r)*HDn + c];
      short8 vv8 = *(const short8*)&Vg[(size_t)(kt*64+r)*HDn + c];
      *(short8*)&Ks[r*72 + c] = kv8;
      #pragma unroll
      for (int j=0;j<8;j++){
        int d = c+j;
        int byteoff = d*128 + ((((r>>3) ^ (d>>3)) & 7)<<4) + (r&7)*2;
        *(ushort*)((char*)VTs + byteoff) = (ushort)vv8[j];
      }
    }
    __syncthreads();
    // ---- QK^T ----
    f32x4 s[4] = {};
    #pragma unroll
    for (int n=0;n<4;n++){
      short8 b0 = *(const short8*)&Ks[(n*16+li)*72 + g*8];
      short8 b1 = *(const short8*)&Ks[(n*16+li)*72 + 32 + g*8];
      s[n] = MFMA16(aq0, b0, s[n]);
      s[n] = MFMA16(aq1, b1, s[n]);
    }
    // ---- scale + causal mask ----
    if (kt == qt){
      #pragma unroll
      for (int n=0;n<4;n++){
        int kvg = n*16 + li;
        #pragma unroll
        for (int reg=0;reg<4;reg++){
          int qg = w*16 + g*4 + reg;
          s[n][reg] = (kvg <= qg) ? s[n][reg]*0.125f : -1e9f;
        }
      }
    } else {
      #pragma unroll
      for (int n=0;n<4;n++)
        #pragma unroll
        for (int reg=0;reg<4;reg++) s[n][reg] *= 0.125f;
    }
    // ---- online softmax (in registers) ----
    #pragma unroll
    for (int reg=0;reg<4;reg++){
      float mt = fmaxf(fmaxf(s[0][reg],s[1][reg]), fmaxf(s[2][reg],s[3][reg]));
      mt = fmaxf(mt, __shfl_xor(mt,1,64));
      mt = fmaxf(mt, __shfl_xor(mt,2,64));
      mt = fmaxf(mt, __shfl_xor(mt,4,64));
      mt = fmaxf(mt, __shfl_xor(mt,8,64));
      float mn = fmaxf(mreg[reg], mt);
      float sc = __expf(mreg[reg]-mn);
      mreg[reg] = mn;
      float p0 = __expf(s[0][reg]-mn), p1 = __expf(s[1][reg]-mn);
      float p2 = __expf(s[2][reg]-mn), p3 = __expf(s[3][reg]-mn);
      s[0][reg]=p0; s[1][reg]=p1; s[2][reg]=p2; s[3][reg]=p3;
      float sm = p0+p1+p2+p3;
      sm += __shfl_xor(sm,1,64);
      sm += __shfl_xor(sm,2,64);
      sm += __shfl_xor(sm,4,64);
      sm += __shfl_xor(sm,8,64);
      lreg[reg] = lreg[reg]*sc + sm;
      #pragma unroll
      for (int n=0;n<4;n++) oacc[n][reg] *= sc;
    }
    // ---- P -> bf16 -> per-wave LDS ----
    #pragma unroll
    for (int n=0;n<4;n++)
      #pragma unroll
      for (int reg=0;reg<4;reg++)
        Ps[w][(g*4+reg)*72 + n*16 + li] = f2bf(s[n][reg]);
    // ---- PV ----
    #pragma unroll
    for (int kk=0;kk<2;kk++){
      short8 ap = *(const short8*)&Ps[w][li*72 + kk*32 + g*8];
      #pragma unroll
      for (int n=0;n<4;n++){
        int d = n*16 + li;
        int gran = ((kk*4 + g) ^ (d>>3)) & 7;
        short8 bv = *(const short8*)((char*)VTs + d*128 + (gran<<4));
        oacc[n] = MFMA16(ap, bv, oacc[n]);
      }
    }
    __syncthreads();
  }
  // ---- write out (B,S,D) bf16 ----
  int b = bh>>3, h = bh&7;
  #pragma unroll
  for (int reg=0;reg<4;reg++){
    int qg = qt*64 + w*16 + g*4 + reg;
    float inv = 1.f/lreg[reg];
    #pragma unroll
    for (int n=0;n<4;n++)
      o[((size_t)(b*Sn+qg))*Dn + h*HDn + n*16 + li] = f2bf(oacc[n][reg]*inv);
  }
}

// --- 5. h = x + h_attn(bf16) ; hm = rms(h_attn)*w -> hm32 (f32) + cat_bf[:, :512] ---

__global__ __launch_bounds__(256) void h_hm_kernel(const float* __restrict__ x,
                                                   const ushort* __restrict__ ha,
                                                   const float* __restrict__ w,
                                                   float* __restrict__ h,
                                                   float* __restrict__ hm32,
                                                   ushort* __restrict__ cat_bf){
  int row=blockIdx.x, tid=threadIdx.x;
  ushort2 a2 = *(const ushort2*)&ha[(size_t)row*Dn + tid*2];
  float ax = bf2f(a2.x), ay = bf2f(a2.y);
  float2 xv = ((const float2*)(x + (size_t)row*Dn))[tid];
  float ss = ax*ax + ay*ay;
  ss = wred_sum(ss);
  __shared__ float red[4];
  int wid=tid>>6, lane=tid&63;
  if (lane==0) red[wid]=ss;
  __syncthreads();
  float tot = red[0]+red[1]+red[2]+red[3];
  float sc = rsqrtf(tot*(1.0f/Dn) + 1e-5f);
  float2 wv = ((const float2*)w)[tid];
  float hm0 = ax*sc*wv.x, hm1 = ay*sc*wv.y;
  ((float2*)(h + (size_t)row*Dn))[tid] = make_float2(xv.x+ax, xv.y+ay);
  ((float2*)(hm32 + (size_t)row*Dn))[tid] = make_float2(hm0, hm1);
  ushort2 u; u.x = f2bf(hm0); u.y = f2bf(hm1);
  *(ushort2*)&cat_bf[(size_t)row*1024 + tid*2] = u;
}

// ---------------- 6. bf16 MFMA logits GEMM + fused top-4 (u64 keys) ----------------

__global__ __launch_bounds__(256) void logits_topk_mfma(const ushort* __restrict__ Abf,
                                                        const ushort* __restrict__ BT,
                                                        u64* __restrict__ keys){
  __shared__ __align__(16) char smem[2*128*40*2];      // 20480 B
  ushort* As = (ushort*)smem;                          // [128][40]
  ushort* Bs = (ushort*)(smem + 128*40*2);             // [128][40]
  float*  Ls = (float*)smem;                           // [32][132] epilogue alias
  int tid=threadIdx.x;
  int w = tid>>6, l = tid&63;
  int wr = w>>1, wc = w&1;
  int g = l>>4, li = l&15;
  int m0 = blockIdx.y*128, n0 = blockIdx.x*128;
  f32x4 acc[4][4] = {};
  for (int kt=0; kt<Dn; kt+=32){
    #pragma unroll
    for (int t=0;t<2;t++){
      int ch = tid + t*256;
      int r = ch>>2, c = (ch&3)*8;
      *(uint4*)&As[r*40+c] = *(const uint4*)&Abf[(size_t)(m0+r)*1024 + kt + c];
      *(uint4*)&Bs[r*40+c] = *(const uint4*)&BT [(size_t)(n0+r)*Dn   + kt + c];
    }
    __syncthreads();
    short8 a[4], b[4];
    #pragma unroll
    for (int i=0;i<4;i++) a[i] = *(const short8*)&As[(wr*64 + i*16 + li)*40 + g*8];
    #pragma unroll
    for (int n=0;n<4;n++) b[n] = *(const short8*)&Bs[(wc*64 + n*16 + li)*40 + g*8];
    #pragma unroll
    for (int i=0;i<4;i++)
      #pragma unroll
      for (int n=0;n<4;n++)
        acc[i][n] = MFMA16(a[i], b[n], acc[i][n]);
    __syncthreads();
  }
  for (int i=0;i<4;i++){
    #pragma unroll
    for (int n=0;n<4;n++)
      #pragma unroll
      for (int reg=0;reg<4;reg++)
        Ls[(wr*16 + g*4 + reg)*132 + wc*64 + n*16 + li] = acc[i][n][reg];
    __syncthreads();
    {
      int r = tid>>3, s = tid&7;
      u64 k0=0,k1=0,k2=0,k3=0;
      #pragma unroll
      for (int c4=0;c4<4;c4++){
        float4 vv = *(const float4*)&Ls[r*132 + s*16 + c4*4];
        int cb = n0 + s*16 + c4*4;
        ins4_64(mkkey(vv.x, cb+0), k0,k1,k2,k3);
        ins4_64(mkkey(vv.y, cb+1), k0,k1,k2,k3);
        ins4_64(mkkey(vv.z, cb+2), k0,k1,k2,k3);
        ins4_64(mkkey(vv.w, cb+3), k0,k1,k2,k3);
      }
      #pragma unroll
      for (int mask=1; mask<8; mask<<=1){
        u64 b0=__shfl_xor(k0,mask,64), b1=__shfl_xor(k1,mask,64);
        u64 b2=__shfl_xor(k2,mask,64), b3=__shfl_xor(k3,mask,64);
        merge4_64(k0,k1,k2,k3, b0,b1,b2,b3);
      }
      if (s==0){
        size_t grow = m0 + ((r>>4)*64 + i*16 + (r&15));
        size_t ob = (grow*128 + blockIdx.x)*4;
        keys[ob+0]=k0; keys[ob+1]=k1; keys[ob+2]=k2; keys[ob+3]=k3;
      }
    }
    __syncthreads();
  }
}

// ---------------- 7. merge 128 tile-partials -> global top4 ----------------

__global__ __launch_bounds__(256) void merge_topk_kernel(const u64* __restrict__ keys,
                                                         int* __restrict__ cand){
  int tid=threadIdx.x, wid=tid>>6, lane=tid&63;
  int row = blockIdx.x*4 + wid;
  size_t base = (size_t)row*512 + (size_t)lane*8;
  u64 k0=keys[base+0],k1=keys[base+1],k2=keys[base+2],k3=keys[base+3];
  merge4_64(k0,k1,k2,k3, keys[base+4],keys[base+5],keys[base+6],keys[base+7]);
  #pragma unroll
  for (int mask=1; mask<64; mask<<=1){
    u64 b0=__shfl_xor(k0,mask,64), b1=__shfl_xor(k1,mask,64);
    u64 b2=__shfl_xor(k2,mask,64), b3=__shfl_xor(k3,mask,64);
    merge4_64(k0,k1,k2,k3, b0,b1,b2,b3);
  }
  if (lane==0){
    cand[(size_t)row*4+0]=(int)(0xFFFFu - (unsigned)(k0 & 0xFFFFu));
    cand[(size_t)row*4+1]=(int)(0xFFFFu - (unsigned)(k1 & 0xFFFFu));
    cand[(size_t)row*4+2]=(int)(0xFFFFu - (unsigned)(k2 & 0xFFFFu));
    cand[(size_t)row*4+3]=(int)(0xFFFFu - (unsigned)(k3 & 0xFFFFu));
  }
}

// ------- 8. gather cand_mem, sim, gumbel select, losses, sel_mem -> cat_bf[:,512:] -------

__global__ __launch_bounds__(256) void select_kernel(const float* __restrict__ hm32,
                                                     const int* __restrict__ cand,
                                                     const int* __restrict__ mem_bank,
                                                     const float* __restrict__ tok_emb,
                                                     const float* __restrict__ gu,
                                                     ushort* __restrict__ cat_bf,
                                                     float* __restrict__ losses){
  __shared__ float cm[4][512];
  __shared__ int ids[32];
  __shared__ float wred[15][4];
  __shared__ int sel_s;
  int row=blockIdx.x, tid=threadIdx.x;
  if (tid<32) ids[tid] = mem_bank[(size_t)cand[(size_t)row*4 + (tid>>3)]*KLn + (tid&7)];
  __syncthreads();
  #pragma unroll
  for (int n=0;n<4;n++){
    float s0=0.f, s1=0.f;
    #pragma unroll
    for (int l=0;l<8;l++){
      const float* e = tok_emb + (size_t)ids[n*8+l]*Dn;
      s0 += e[tid]; s1 += e[tid+256];
    }
    cm[n][tid]=s0*0.125f; cm[n][tid+256]=s1*0.125f;
  }
  __syncthreads();
  float hm0 = hm32[(size_t)row*Dn + tid], hm1 = hm32[(size_t)row*Dn + 256 + tid];
  float c0[4], c1[4];
  #pragma unroll
  for (int n=0;n<4;n++){ c0[n]=cm[n][tid]; c1[n]=cm[n][tid+256]; }
  float p[15];
  p[0]=hm0*hm0+hm1*hm1;
  #pragma unroll
  for (int n=0;n<4;n++) p[1+n]=hm0*c0[n]+hm1*c1[n];
  int qi=5;
  #pragma unroll
  for (int n=0;n<4;n++)
    #pragma unroll
    for (int m=n;m<4;m++) p[qi++]=c0[n]*c0[m]+c1[n]*c1[m];
  int wid=tid>>6, lane=tid&63;
  #pragma unroll
  for (int i=0;i<15;i++) p[i]=wred_sum(p[i]);
  if (lane==0){
    #pragma unroll
    for (int i=0;i<15;i++) wred[i][wid]=p[i];
  }
  __syncthreads();
  if (tid==0){
    float tot[15];
    #pragma unroll
    for (int i=0;i<15;i++) tot[i]=wred[i][0]+wred[i][1]+wred[i][2]+wred[i][3];
    float hn2 = fmaxf(sqrtf(tot[0]), 1e-8f);
    const int diag[4]={5,9,12,14};
    float sim[4], dn[4];
    #pragma unroll
    for (int n=0;n<4;n++){
      float cn = sqrtf(tot[diag[n]]);
      sim[n] = tot[1+n]/(hn2*fmaxf(cn,1e-8f));
      dn[n]  = fmaxf(cn,1e-12f);
    }
    float best=-1e30f; int sel=0;
    #pragma unroll
    for (int n=0;n<4;n++){
      float u = gu[(size_t)row*4+n];
      float g = -logf(-logf(u + 1e-20f) + 1e-20f);
      float a = sim[n]+g;
      if (a>best){ best=a; sel=n; }
    }
    atomicAdd(&losses[0], sim[sel]);
    const int cross[6]={6,7,8,10,11,13};
    const int cn_[6]={0,0,0,1,1,2}, cm_[6]={1,2,3,2,3,3};
    float dv=0.f;
    #pragma unroll
    for (int t=0;t<6;t++) dv += 2.f*tot[cross[t]]/(dn[cn_[t]]*dn[cm_[t]]);
    atomicAdd(&losses[1], dv);
    sel_s=sel;
  }
  __syncthreads();
  int sel=sel_s;
  cat_bf[(size_t)row*1024 + 512 + tid]       = f2bf(cm[sel][tid]);
  cat_bf[(size_t)row*1024 + 512 + 256 + tid] = f2bf(cm[sel][tid+256]);
}

// ---------------- 12. out = h + sigmoid(g+bg)*(m+bm); losses tail ----------------

__global__ __launch_bounds__(256) void final_kernel(const float* __restrict__ h,
                                                    const float* __restrict__ g,
                                                    const float* __restrict__ m,
                                                    const float* __restrict__ bg,
                                                    const float* __restrict__ bm,
                                                    const float* __restrict__ losses,
                                                    float* __restrict__ out){
  int idx = blockIdx.x*256 + threadIdx.x;
  int n = idx & (Dn-1);
  float gl = g[idx] + bg[n];
  float ml = m[idx] + bm[n];
  float gate = 1.f/(1.f+__expf(-gl));
  out[idx] = h[idx] + gate*ml;
  if (idx==0){
    out[(size_t)Mn*Dn]     = -losses[0]*(1.f/(float)Mn);
    out[(size_t)Mn*Dn + 1] =  losses[1]*(1.f/(float)(Mn*NCn*(NCn-1)));
  }
}

// ---------------- launch ----------------

extern "C" void kernel_launch(void* const* d_in, const int* in_sizes, int n_in,
                              void* d_out, int out_size, void* d_ws, size_t ws_size,
                              hipStream_t stream){
  const float* x           = (const float*)d_in[0];
  const float* pos_cos     = (const float*)d_in[1];
  const float* pos_sin     = (const float*)d_in[2];
  const int*   memory_bank = (const int*)  d_in[3];
  const float* tok_emb     = (const float*)d_in[4];
  const float* wq          = (const float*)d_in[5];
  const float* wk          = (const float*)d_in[6];
  const float* wv          = (const float*)d_in[7];
  const float* wo          = (const float*)d_in[8];
  const float* attn_norm_w = (const float*)d_in[9];
  const float* mem_norm_w  = (const float*)d_in[10];
  const float* w_gate      = (const float*)d_in[11];
  const float* wg_fuse     = (const float*)d_in[12];
  const float* bg_fuse     = (const float*)d_in[13];
  const float* wm_fuse     = (const float*)d_in[14];
  const float* bm_fuse     = (const float*)d_in[15];
  const float* gumbel_u    = (const float*)d_in[16];
  float* out = (float*)d_out;

  char* ws = (char*)d_ws;
  const size_t MB = 1u<<20;
  // Lifetime-checked layout (sizes: Q/K/V/hn/pv/h_attn_bf 4MB each; f32 bufs 8MB; keys 16MB):
  //  0-16 : BTg (live until logits_topk)
  // 16-18 : wqT,wkT,wvT,woT   18-19: wgfT   19-20: wmfT
  // 20-24 : hn_bf (dead after V gemm) -> pv_bf (dead after wo gemm)
  // 24-28 : qb_bf  (dead after attn)
  // 28-32 : kb_bf  (dead after attn)
  // 32-36 : vb_bf  (dead after attn)
  // 36-40 : h_attn_bf (dead after h_hm)
  // 40-48 : hbuf f32   (live until final)
  // 48-56 : hm32 f32   (live until select)
  // 56-64 : cat_bf     (live until fuse gemms)
  // 20-36 : keys 16MB  (written by logits_topk: pv/q/k/v all dead; dead after merge)
  // 20-28 : gbuf f32   (written after select; keys dead)
  // 28-36 : mbuf f32
  // 64MB  : cand (64KB)   64MB+64KB: losses (8B)
  ushort* BTg       = (ushort*)(ws);
  ushort* wqT       = (ushort*)(ws + 16*MB);
  ushort* wkT       = (ushort*)(ws + 16*MB + 512*1024);
  ushort* wvT       = (ushort*)(ws + 17*MB);
  ushort* woT       = (ushort*)(ws + 17*MB + 512*1024);
  ushort* wgfT      = (ushort*)(ws + 18*MB);
  ushort* wmfT      = (ushort*)(ws + 19*MB);
  ushort* hn_bf     = (ushort*)(ws + 20*MB);
  ushort* pv_bf     = (ushort*)(ws + 20*MB);
  ushort* qb_bf     = (ushort*)(ws + 24*MB);
  ushort* kb_bf     = (ushort*)(ws + 28*MB);
  ushort* vb_bf     = (ushort*)(ws + 32*MB);
  ushort* h_attn_bf = (ushort*)(ws + 36*MB);
  float*  hbuf      = (float*)(ws + 40*MB);
  float*  hm32      = (float*)(ws + 48*MB);
  ushort* cat_bf    = (ushort*)(ws + 56*MB);
  u64*    keys      = (u64*)  (ws + 20*MB);
  float*  gbuf      = (float*)(ws + 20*MB);
  float*  mbuf      = (float*)(ws + 28*MB);
  int*    cand      = (int*)  (ws + 64*MB);
  float*  losses    = (float*)(ws + 64*MB + 65536);

  hipMemsetAsync(losses, 0, 2*sizeof(float), stream);

  convT_kernel<<<dim3(8,8),   256, 0, stream>>>(wq,      wqT,  512,  512);
  convT_kernel<<<dim3(8,8),   256, 0, stream>>>(wk,      wkT,  512,  512);
  convT_kernel<<<dim3(8,8),   256, 0, stream>>>(wv,      wvT,  512,  512);
  convT_kernel<<<dim3(8,8),   256, 0, stream>>>(wo,      woT,  512,  512);
  convT_kernel<<<dim3(8,16),  256, 0, stream>>>(wg_fuse, wgfT, 512,  1024);
  convT_kernel<<<dim3(8,16),  256, 0, stream>>>(wm_fuse, wmfT, 512,  1024);
  convT_kernel<<<dim3(256,8), 256, 0, stream>>>(w_gate,  BTg,  KNn,  512);

  rmsnorm_kernel<<<Mn, 256, 0, stream>>>(x, attn_norm_w, hn_bf);

  dim3 g64(Dn/64, Mn/64);   // (8, 64)
  gemm_bf16<1><<<g64, 256, 0, stream>>>(hn_bf, 512, wqT, 512, qb_bf, 0, pos_cos, pos_sin);
  gemm_bf16<1><<<g64, 256, 0, stream>>>(hn_bf, 512, wkT, 512, kb_bf, 0, pos_cos, pos_sin);
  gemm_bf16<2><<<g64, 256, 0, stream>>>(hn_bf, 512, wvT, 512, vb_bf, 0, nullptr, nullptr);

  attn_mfma<<<dim3(Sn/64, Bn*NHn), 256, 0, stream>>>(qb_bf, kb_bf, vb_bf, pv_bf);

  gemm_bf16<3><<<g64, 256, 0, stream>>>(pv_bf, 512, woT, 512, h_attn_bf, 512, nullptr, nullptr);

  h_hm_kernel<<<Mn, 256, 0, stream>>>(x, h_attn_bf, mem_norm_w, hbuf, hm32, cat_bf);

  logits_topk_mfma<<<dim3(KNn/128, Mn/128), 256, 0, stream>>>(cat_bf, BTg, keys);
  merge_topk_kernel<<<Mn/4, 256, 0, stream>>>(keys, cand);

  select_kernel<<<Mn, 256, 0, stream>>>(hm32, cand, memory_bank, tok_emb, gumbel_u, cat_bf, losses);

  gemm_bf16<0><<<g64, 256, 0, stream>>>(cat_bf, 1024, wgfT, 1024, gbuf, 512, nullptr, nullptr);
  gemm_bf16<0><<<g64, 256, 0, stream>>>(cat_bf, 1024, wmfT, 1024, mbuf, 512, nullptr, nullptr);

  final_kernel<<<(Mn*Dn)/256, 256, 0, stream>>>(hbuf, gbuf, mbuf, bg_fuse, bm_fuse, losses, out);
}